// Round 10
// baseline (780.172 us; speedup 1.0000x reference)
//
#include <hip/hip_runtime.h>
#include <hip/hip_bf16.h>

#define HDIM 128
#define FDIM 32
#define GGR  64
#define SCAN_CHUNK 2048
#define FILL_CHUNK 1024
#define FILL_WIN 16

typedef __attribute__((ext_vector_type(8))) short bf16x8;
typedef __attribute__((ext_vector_type(4))) float f32x4;

__device__ __forceinline__ float fsig(float x) {
  return __builtin_amdgcn_rcpf(1.f + __expf(-x));
}
// tanh(x) = 1 - 2/(e^{2x}+1); saturates correctly at +/-inf via rcp(inf)=0.
__device__ __forceinline__ float ftanh(float x) {
  return 1.f - 2.f * __builtin_amdgcn_rcpf(1.f + __expf(2.f * x));
}

__device__ __forceinline__ bf16x8 pack_bf16x8(float4 a, float4 b) {
  union { bf16x8 v; __hip_bfloat162 h[4]; } u;
  u.h[0] = __float22bfloat162_rn(make_float2(a.x, a.y));
  u.h[1] = __float22bfloat162_rn(make_float2(a.z, a.w));
  u.h[2] = __float22bfloat162_rn(make_float2(b.x, b.y));
  u.h[3] = __float22bfloat162_rn(make_float2(b.z, b.w));
  return u.v;
}

// Fragment-order swizzled LDS block index for a 64-row x 128-col bf16 tile.
__device__ __forceinline__ int ablk(int kb, int m) {
  return (kb << 6) + (m & 56) + ((m ^ kb) & 7);
}

__device__ __forceinline__ void stage64(const unsigned short* __restrict__ g,
                                        short* __restrict__ s, int n0, int N, int t) {
#pragma unroll
  for (int r = 0; r < 2; ++r) {
    int idx = r * 512 + t;
    int m = idx >> 4, c8 = idx & 15;
    int gn = n0 + m;
    uint4 v = make_uint4(0u, 0u, 0u, 0u);
    if (gn < N) v = *(const uint4*)(g + (size_t)gn * HDIM + c8 * 8);
    *(uint4*)(s + ablk(c8, m) * 8) = v;
  }
}

// ---------------- CSR histogram with rank capture ----------------
__global__ __launch_bounds__(256) void k_hist(const int* __restrict__ dst, int* __restrict__ deg,
                                              unsigned short* __restrict__ rank,
                                              long long E) {
  long long e = (long long)blockIdx.x * 256 + threadIdx.x;
  if (e < E) {
    int old = atomicAdd(&deg[dst[e]], 1);
    rank[e] = (unsigned short)old;
  }
}

// ---------------- fused: windowed CSR fill + embed MFMA (independent work) ----------------
// Even blocks -> embed tiles (XCD-swizzled), odd blocks -> fill chunks, so both
// types co-reside on every CU and fill's scatter latency hides under embed's MFMA.
__global__ __launch_bounds__(256) void k_embed_fill(const float* __restrict__ x,
                                                    const unsigned short* __restrict__ W0b,
                                                    unsigned short* __restrict__ hb,
                                                    float* __restrict__ xemb,
                                                    const unsigned short* __restrict__ convT0,
                                                    unsigned short* __restrict__ m_out,
                                                    int N,
                                                    const int* __restrict__ src,
                                                    const int* __restrict__ dst,
                                                    const unsigned short* __restrict__ rank,
                                                    const int* __restrict__ rowstart,
                                                    int* __restrict__ csr,
                                                    long long E, int TP, int FB, int q8) {
  __shared__ short sE[16 * 64 * 8];
  int p = blockIdx.x;
  int M2 = ((TP < FB) ? TP : FB) * 2;
  bool isFill; int idx;
  if (p < M2) { isFill = (p & 1); idx = p >> 1; }
  else { idx = p - (M2 >> 1); isFill = (FB > TP); }

  if (isFill) {
    // ---- windowed CSR fill chunk (aliases sE for its LDS) ----
    int* sd = (int*)sE;                       // 1024 ints
    int* ss = sd + FILL_CHUNK;                // 1024 ints
    unsigned short* sr = (unsigned short*)(ss + FILL_CHUNK);  // 1024 u16
    long long base = (long long)idx * FILL_CHUNK;
    int cnt = (int)((E - base < FILL_CHUNK) ? (E - base) : FILL_CHUNK);
    for (int i = threadIdx.x; i < cnt; i += 256) {
      sd[i] = dst[base + i];
      ss[i] = src[base + i];
      sr[i] = rank[base + i];
    }
    __syncthreads();
    int nw = (N + FILL_WIN - 1) / FILL_WIN;
#pragma unroll 1
    for (int w = 0; w < FILL_WIN; ++w) {
      int lo = w * nw, hi = lo + nw;
      for (int i = threadIdx.x; i < cnt; i += 256) {
        int d = sd[i];
        if (d >= lo && d < hi)
          csr[rowstart[d] + sr[i]] = ss[i];
      }
      __syncthreads();
    }
    return;
  }

  // ---- embed tile (XCD-chunked map) ----
  int T = (idx & 7) * q8 + (idx >> 3);
  int n0 = T * 64;
  if (n0 >= N) return;
  int t = threadIdx.x;
  int w = t >> 6, l = t & 63;
  int lm = l & 15, lq = l >> 4;
  int j0 = w * 32;
  bf16x8 b0 = *(const bf16x8*)(W0b + (size_t)(j0 + lm) * FDIM + lq * 8);
  bf16x8 b1 = *(const bf16x8*)(W0b + (size_t)(j0 + 16 + lm) * FDIM + lq * 8);
  f32x4 acc0[4], acc1[4];
#pragma unroll
  for (int i = 0; i < 4; ++i) { acc0[i] = (f32x4){0.f,0.f,0.f,0.f}; acc1[i] = (f32x4){0.f,0.f,0.f,0.f}; }
#pragma unroll
  for (int tt = 0; tt < 4; ++tt) {
    int rg = n0 + tt * 16 + lm;
    bf16x8 a = (bf16x8){0,0,0,0,0,0,0,0};
    if (rg < N) {
      const float4* xr = (const float4*)x + (size_t)rg * 8 + lq * 2;
      a = pack_bf16x8(xr[0], xr[1]);
    }
    acc0[tt] = __builtin_amdgcn_mfma_f32_16x16x32_bf16(a, b0, acc0[tt], 0, 0, 0);
    acc1[tt] = __builtin_amdgcn_mfma_f32_16x16x32_bf16(a, b1, acc1[tt], 0, 0, 0);
  }
#pragma unroll
  for (int g = 0; g < 2; ++g) {
    int j = j0 + g * 16 + lm;
#pragma unroll
    for (int tt = 0; tt < 4; ++tt)
#pragma unroll
      for (int r = 0; r < 4; ++r) {
        int m = tt * 16 + lq * 4 + r;
        int node = n0 + m;
        float v = g ? acc1[tt][r] : acc0[tt][r];
        float e = fsig(v);
        __hip_bfloat16 eb = __float2bfloat16(e);
        ((__hip_bfloat16*)sE)[ablk(j >> 3, m) * 8 + (j & 7)] = eb;
        if (node < N) {
          size_t off = (size_t)node * HDIM + j;
          xemb[off] = e;
          ((__hip_bfloat16*)hb)[off] = eb;
        }
      }
  }
  __syncthreads();
  // transform phase: m0 = E @ conv_w[0]  (wT[j][k])
#pragma unroll
  for (int g = 0; g < 2; ++g) {
    int jg = j0 + g * 16;
    f32x4 macc[4];
#pragma unroll
    for (int i = 0; i < 4; ++i) macc[i] = (f32x4){0.f,0.f,0.f,0.f};
#pragma unroll
    for (int ks = 0; ks < 4; ++ks) {
      bf16x8 b = *(const bf16x8*)(convT0 + (size_t)(jg + lm) * HDIM + ks * 32 + lq * 8);
      int kb = ks * 4 + lq;
#pragma unroll
      for (int tt = 0; tt < 4; ++tt) {
        bf16x8 a = *(const bf16x8*)(sE + ablk(kb, tt * 16 + lm) * 8);
        macc[tt] = __builtin_amdgcn_mfma_f32_16x16x32_bf16(a, b, macc[tt], 0, 0, 0);
      }
    }
    int j = jg + lm;
#pragma unroll
    for (int tt = 0; tt < 4; ++tt)
#pragma unroll
      for (int r = 0; r < 4; ++r) {
        int node = n0 + tt * 16 + lq * 4 + r;
        if (node < N)
          ((__hip_bfloat16*)m_out)[(size_t)node * HDIM + j] = __float2bfloat16(macc[tt][r]);
      }
  }
}

// ---------------- weight prep: fp32 -> bf16 (W0, GRU mats, conv transpose) ----------------
__global__ __launch_bounds__(256) void k_prep_w(const float* __restrict__ w_ih,
                                                const float* __restrict__ w_hh,
                                                const float* __restrict__ conv_w,
                                                const float* __restrict__ W0,
                                                unsigned short* __restrict__ wIb,
                                                unsigned short* __restrict__ wHb,
                                                unsigned short* __restrict__ convTb,
                                                unsigned short* __restrict__ W0b,
                                                int L) {
  int i = blockIdx.x * 256 + threadIdx.x;
  if (i < HDIM * FDIM) ((__hip_bfloat16*)W0b)[i] = __float2bfloat16(W0[i]);
  if (i < 384 * HDIM) {
    ((__hip_bfloat16*)wIb)[i] = __float2bfloat16(w_ih[i]);
    ((__hip_bfloat16*)wHb)[i] = __float2bfloat16(w_hh[i]);
  }
  int total = L * HDIM * HDIM;
  if (i < total) {
    int l = i >> 14, rem = i & 16383, j = rem >> 7, k = rem & 127;
    ((__hip_bfloat16*)convTb)[i] = __float2bfloat16(conv_w[(l << 14) + (k << 7) + j]);
  }
}

__global__ __launch_bounds__(256) void k_block_sum(const int* __restrict__ deg,
                                                   int* __restrict__ bsum, int N) {
  int base = blockIdx.x * SCAN_CHUNK + threadIdx.x * 8;
  int s = 0;
#pragma unroll
  for (int u = 0; u < 8; ++u) { int i = base + u; if (i < N) s += deg[i]; }
#pragma unroll
  for (int o = 32; o; o >>= 1) s += __shfl_down(s, o, 64);
  __shared__ int wsum[4];
  if ((threadIdx.x & 63) == 0) wsum[threadIdx.x >> 6] = s;
  __syncthreads();
  if (threadIdx.x == 0) bsum[blockIdx.x] = wsum[0] + wsum[1] + wsum[2] + wsum[3];
}

__global__ void k_scan_bsums(int* __restrict__ bsum, int nb) {
  if (blockIdx.x == 0 && threadIdx.x == 0) {
    int run = 0;
    for (int i = 0; i < nb; ++i) { int v = bsum[i]; bsum[i] = run; run += v; }
  }
}

__global__ __launch_bounds__(256) void k_scan_chunks(const int* __restrict__ deg,
                                                     const int* __restrict__ bsum,
                                                     int* __restrict__ rowstart,
                                                     int N, int Etot) {
  __shared__ int ts[256];
  int base = blockIdx.x * SCAN_CHUNK + threadIdx.x * 8;
  int loc[8]; int s = 0;
#pragma unroll
  for (int u = 0; u < 8; ++u) {
    int i = base + u; loc[u] = s;
    s += (i < N) ? deg[i] : 0;
  }
  ts[threadIdx.x] = s;
  __syncthreads();
  for (int o = 1; o < 256; o <<= 1) {
    int v = (threadIdx.x >= o) ? ts[threadIdx.x - o] : 0;
    __syncthreads();
    ts[threadIdx.x] += v;
    __syncthreads();
  }
  int texcl = (threadIdx.x ? ts[threadIdx.x - 1] : 0) + bsum[blockIdx.x];
#pragma unroll
  for (int u = 0; u < 8; ++u) {
    int i = base + u;
    if (i < N) rowstart[i] = texcl + loc[u];
  }
  if (blockIdx.x == 0 && threadIdx.x == 0) rowstart[N] = Etot;
}

// ---------------- agg[n] = sum_{row n} m[src]; wave/node, 8 edges x 2KB in flight ----------------
__global__ __launch_bounds__(256) void k_gather(const int* __restrict__ csr,
                                                const int* __restrict__ rowstart,
                                                const unsigned short* __restrict__ m,
                                                unsigned short* __restrict__ agg, int N, int q8) {
  int p = blockIdx.x;
  int G = (p & 7) * q8 * 16 + (p >> 3);
  int wv = threadIdx.x >> 6, l = threadIdx.x & 63;
  int n = G * 4 + wv;
  if (n >= N) return;
  int eq = l >> 3;      // edge slot 0..7
  int jb = l & 7;       // channel group (16 chans, 32B)
  int beg = rowstart[n], end = rowstart[n + 1];
  float acc[16];
#pragma unroll
  for (int i = 0; i < 16; ++i) acc[i] = 0.f;
  for (int e0 = beg; e0 < end; e0 += 8) {
    int e = e0 + eq;
    uint4 v0 = make_uint4(0u, 0u, 0u, 0u);
    uint4 v1 = make_uint4(0u, 0u, 0u, 0u);
    if (e < end) {
      int s = csr[e];
      const uint4* row = (const uint4*)(m + (size_t)s * HDIM + jb * 16);
      v0 = row[0];
      v1 = row[1];
    }
    acc[0]  += __uint_as_float(v0.x << 16);
    acc[1]  += __uint_as_float(v0.x & 0xffff0000u);
    acc[2]  += __uint_as_float(v0.y << 16);
    acc[3]  += __uint_as_float(v0.y & 0xffff0000u);
    acc[4]  += __uint_as_float(v0.z << 16);
    acc[5]  += __uint_as_float(v0.z & 0xffff0000u);
    acc[6]  += __uint_as_float(v0.w << 16);
    acc[7]  += __uint_as_float(v0.w & 0xffff0000u);
    acc[8]  += __uint_as_float(v1.x << 16);
    acc[9]  += __uint_as_float(v1.x & 0xffff0000u);
    acc[10] += __uint_as_float(v1.y << 16);
    acc[11] += __uint_as_float(v1.y & 0xffff0000u);
    acc[12] += __uint_as_float(v1.z << 16);
    acc[13] += __uint_as_float(v1.z & 0xffff0000u);
    acc[14] += __uint_as_float(v1.w << 16);
    acc[15] += __uint_as_float(v1.w & 0xffff0000u);
  }
#pragma unroll
  for (int i = 0; i < 16; ++i) {
    acc[i] += __shfl_xor(acc[i], 8, 64);
    acc[i] += __shfl_xor(acc[i], 16, 64);
    acc[i] += __shfl_xor(acc[i], 32, 64);
  }
  if (eq == 0) {
    union { uint4 v[2]; __hip_bfloat162 h[8]; } o;
#pragma unroll
    for (int i = 0; i < 8; ++i)
      o.h[i] = __float22bfloat162_rn(make_float2(acc[2 * i], acc[2 * i + 1]));
    uint4* dstp = (uint4*)(agg + (size_t)n * HDIM + jb * 16);
    dstp[0] = o.v[0];
    dstp[1] = o.v[1];
  }
}

// ---------------- fused GRU: MFMA gi/gh + elementwise + next transform OR readout ----------------
// Round-5 core (untouchable schedule). Final layer (wT==nullptr): instead of
// writing h_new, fuse the readout dot: part = relu(hn)*w1[j], shfl-reduce over
// the 16-lane lm group, LDS-atomic into a 64-float tile, write out_raw/out_unc.
__global__ __launch_bounds__(512, 4) void k_gru_mfma(const unsigned short* __restrict__ aggb,
                                                  const unsigned short* __restrict__ hb,
                                                  const unsigned short* __restrict__ wI,
                                                  const unsigned short* __restrict__ wH,
                                                  const float* __restrict__ b_ih,
                                                  const float* __restrict__ b_hh,
                                                  unsigned short* __restrict__ hnewb,
                                                  const unsigned short* __restrict__ wT,
                                                  unsigned short* __restrict__ m_out,
                                                  const float* __restrict__ w1,
                                                  const float* __restrict__ b1,
                                                  float* __restrict__ out_raw,
                                                  float* __restrict__ out_unc,
                                                  int N, int q8) {
  __shared__ short sAg[16 * 64 * 8];
  __shared__ short sH[16 * 64 * 8];
  __shared__ float sOut[64];
  int p = blockIdx.x;
  int T = (p & 7) * q8 + (p >> 3);
  int n0 = T * 64;
  if (n0 >= N) return;
  int t = threadIdx.x;
  stage64(aggb, sAg, n0, N, t);
  stage64(hb, sH, n0, N, t);
  if (!wT && t < 64) sOut[t] = 0.f;
  int w = t >> 6, l = t & 63;
  int j0 = w * 16;
  int lm = l & 15, lq = l >> 4;
  int j = j0 + lm;
  float bir = b_ih[j], biz = b_ih[j + 128], bin = b_ih[j + 256];
  float bhr = b_hh[j], bhz = b_hh[j + 128], bhn = b_hh[j + 256];
  float w1j = 0.f;
  if (!wT) w1j = w1[j];
  __syncthreads();
  f32x4 aR[4], aZ[4], aNi[4], aNh[4];
#pragma unroll
  for (int i = 0; i < 4; ++i) {
    aR[i] = (f32x4){0.f,0.f,0.f,0.f}; aZ[i] = (f32x4){0.f,0.f,0.f,0.f};
    aNi[i] = (f32x4){0.f,0.f,0.f,0.f}; aNh[i] = (f32x4){0.f,0.f,0.f,0.f};
  }
#pragma unroll
  for (int ks = 0; ks < 4; ++ks) {
    size_t rI = (size_t)(j0 + lm) * HDIM + ks * 32 + lq * 8;
    bf16x8 bIr = *(const bf16x8*)(wI + rI);
    bf16x8 bIz = *(const bf16x8*)(wI + rI + 128 * HDIM);
    bf16x8 bIn = *(const bf16x8*)(wI + rI + 256 * HDIM);
    bf16x8 bHr = *(const bf16x8*)(wH + rI);
    bf16x8 bHz = *(const bf16x8*)(wH + rI + 128 * HDIM);
    bf16x8 bHn = *(const bf16x8*)(wH + rI + 256 * HDIM);
    int kb = ks * 4 + lq;
#pragma unroll
    for (int tt = 0; tt < 4; ++tt) {
      bf16x8 a = *(const bf16x8*)(sAg + ablk(kb, tt * 16 + lm) * 8);
      bf16x8 h = *(const bf16x8*)(sH + ablk(kb, tt * 16 + lm) * 8);
      aR[tt] = __builtin_amdgcn_mfma_f32_16x16x32_bf16(a, bIr, aR[tt], 0, 0, 0);
      aR[tt] = __builtin_amdgcn_mfma_f32_16x16x32_bf16(h, bHr, aR[tt], 0, 0, 0);
      aZ[tt] = __builtin_amdgcn_mfma_f32_16x16x32_bf16(a, bIz, aZ[tt], 0, 0, 0);
      aZ[tt] = __builtin_amdgcn_mfma_f32_16x16x32_bf16(h, bHz, aZ[tt], 0, 0, 0);
      aNi[tt] = __builtin_amdgcn_mfma_f32_16x16x32_bf16(a, bIn, aNi[tt], 0, 0, 0);
      aNh[tt] = __builtin_amdgcn_mfma_f32_16x16x32_bf16(h, bHn, aNh[tt], 0, 0, 0);
    }
  }
  // all waves must finish reading sAg before it is reused as the h_new tile
  __syncthreads();
#pragma unroll
  for (int tt = 0; tt < 4; ++tt)
#pragma unroll
    for (int r = 0; r < 4; ++r) {
      int m = tt * 16 + lq * 4 + r;
      int node = n0 + m;
      float hp = __bfloat162float(((const __hip_bfloat16*)sH)[ablk(j >> 3, m) * 8 + (j & 7)]);
      float rg = fsig(aR[tt][r] + bir + bhr);
      float zg = fsig(aZ[tt][r] + biz + bhz);
      float nv = aNi[tt][r] + bin + rg * (aNh[tt][r] + bhn);
      float th = ftanh(nv);
      float hn = (1.f - zg) * th + zg * hp;
      if (wT) {
        __hip_bfloat16 hnb = __float2bfloat16(hn);
        ((__hip_bfloat16*)sAg)[ablk(j >> 3, m) * 8 + (j & 7)] = hnb;
        if (node < N)
          ((__hip_bfloat16*)hnewb)[(size_t)node * HDIM + j] = hnb;
      } else {
        float prt = (node < N) ? fmaxf(hn, 0.f) * w1j : 0.f;
        prt += __shfl_xor(prt, 1, 64);
        prt += __shfl_xor(prt, 2, 64);
        prt += __shfl_xor(prt, 4, 64);
        prt += __shfl_xor(prt, 8, 64);
        if (lm == 0) atomicAdd(&sOut[m], prt);
      }
    }
  if (wT) {
    __syncthreads();
    // m_next = h_new @ conv_w[l+1] straight from the LDS tile
    f32x4 macc[4];
#pragma unroll
    for (int i = 0; i < 4; ++i) macc[i] = (f32x4){0.f,0.f,0.f,0.f};
#pragma unroll
    for (int ks = 0; ks < 4; ++ks) {
      bf16x8 b = *(const bf16x8*)(wT + (size_t)(j0 + lm) * HDIM + ks * 32 + lq * 8);
      int kb = ks * 4 + lq;
#pragma unroll
      for (int tt = 0; tt < 4; ++tt) {
        bf16x8 a = *(const bf16x8*)(sAg + ablk(kb, tt * 16 + lm) * 8);
        macc[tt] = __builtin_amdgcn_mfma_f32_16x16x32_bf16(a, b, macc[tt], 0, 0, 0);
      }
    }
#pragma unroll
    for (int tt = 0; tt < 4; ++tt)
#pragma unroll
      for (int r = 0; r < 4; ++r) {
        int node = n0 + tt * 16 + lq * 4 + r;
        if (node < N)
          ((__hip_bfloat16*)m_out)[(size_t)node * HDIM + j] = __float2bfloat16(macc[tt][r]);
      }
  } else {
    __syncthreads();
    if (t < 64) {
      int node = n0 + t;
      if (node < N) {
        float o = sOut[t] + b1[0];
        out_raw[node] = o;
        out_unc[node] = o;
      }
    }
  }
}

__global__ __launch_bounds__(256) void k_graph_reduce(const float* __restrict__ out_raw,
                                                      const int* __restrict__ batch,
                                                      float* __restrict__ gsum,
                                                      float* __restrict__ gcnt,
                                                      int N) {
  __shared__ float ls[GGR], lc[GGR];
  int t = threadIdx.x;
  if (t < GGR) { ls[t] = 0.f; lc[t] = 0.f; }
  __syncthreads();
  for (int n = blockIdx.x * 256 + t; n < N; n += gridDim.x * 256) {
    int g = batch[n];
    atomicAdd(&ls[g], out_raw[n]);
    atomicAdd(&lc[g], 1.f);
  }
  __syncthreads();
  if (t < GGR) {
    unsafeAtomicAdd(&gsum[t], ls[t]);
    unsafeAtomicAdd(&gcnt[t], lc[t]);
  }
}

__global__ __launch_bounds__(256) void k_correct(const float* __restrict__ out_raw,
                                                 const int* __restrict__ batch,
                                                 const float* __restrict__ gsum,
                                                 const float* __restrict__ gcnt,
                                                 float* __restrict__ corrected, int N) {
  int n = blockIdx.x * 256 + threadIdx.x;
  if (n < N) {
    int g = batch[n];
    corrected[n] = out_raw[n] - gsum[g] / fmaxf(gcnt[g], 1.f);
  }
}

extern "C" void kernel_launch(void* const* d_in, const int* in_sizes, int n_in,
                              void* d_out, int out_size, void* d_ws, size_t ws_size,
                              hipStream_t stream) {
  const float* x      = (const float*)d_in[0];
  const int*   ei     = (const int*)d_in[1];
  const int*   batch  = (const int*)d_in[2];
  const float* W0     = (const float*)d_in[4];
  const float* conv_w = (const float*)d_in[5];
  const float* w_ih   = (const float*)d_in[6];
  const float* b_ih   = (const float*)d_in[7];
  const float* w_hh   = (const float*)d_in[8];
  const float* b_hh   = (const float*)d_in[9];
  const float* lin1_w = (const float*)d_in[10];
  const float* lin1_b = (const float*)d_in[11];

  int N = in_sizes[0] / FDIM;
  long long E = in_sizes[1] / 2;
  int L = in_sizes[5] / (HDIM * HDIM);

  const int* src = ei;
  const int* dstv = ei + E;

  float* out_corrected = (float*)d_out;
  float* out_xemb = out_corrected + N;
  float* out_unc  = out_xemb + (size_t)N * HDIM;

  char* p = (char*)d_ws;
  unsigned short* x0 = (unsigned short*)p; p += (size_t)N * HDIM * 2;
  unsigned short* x1 = (unsigned short*)p; p += (size_t)N * HDIM * 2;
  unsigned short* x2 = (unsigned short*)p; p += (size_t)N * HDIM * 2;
  float* out_raw = (float*)p;        p += (size_t)((N + 3) & ~3) * 4;
  float* gsum = (float*)p;           p += GGR * 4;
  float* gcnt = (float*)p;           p += GGR * 4;
  int* deg = (int*)p;                p += (size_t)((N + 3) & ~3) * 4;
  int* rowstart = (int*)p;           p += (size_t)(N + 4) * 4;
  int nb = (N + SCAN_CHUNK - 1) / SCAN_CHUNK;
  int* bsum = (int*)p;               p += (size_t)((nb + 63) & ~63) * 4;
  int* csr = (int*)p;                p += (size_t)E * 4;
  unsigned short* rankb = (unsigned short*)p;  p += (size_t)((E + 3) & ~3) * 2;
  unsigned short* wIb = (unsigned short*)p;    p += 384 * HDIM * 2;
  unsigned short* wHb = (unsigned short*)p;    p += 384 * HDIM * 2;
  unsigned short* convTb = (unsigned short*)p; p += (size_t)L * HDIM * HDIM * 2;
  unsigned short* W0b = (unsigned short*)p;

  int prep_total = (384 * HDIM > L * HDIM * HDIM) ? 384 * HDIM : L * HDIM * HDIM;
  k_prep_w<<<(prep_total + 255) / 256, 256, 0, stream>>>(w_ih, w_hh, conv_w, W0, wIb, wHb, convTb, W0b, L);

  hipMemsetAsync(deg, 0, (size_t)N * sizeof(int), stream);
  hipMemsetAsync(gsum, 0, 2 * GGR * sizeof(float), stream);

  int nblk = (N + 63) / 64;
  int TP = (nblk + 7) & ~7;   // embed/gru tile count padded to multiple of 8 XCDs
  int q8 = TP / 8;
  int histBlocks = (int)((E + 255) / 256);
  int FB = (int)((E + FILL_CHUNK - 1) / FILL_CHUNK);

  k_hist<<<histBlocks, 256, 0, stream>>>(dstv, deg, rankb, E);
  k_block_sum<<<nb, 256, 0, stream>>>(deg, bsum, N);
  k_scan_bsums<<<1, 64, 0, stream>>>(bsum, nb);
  k_scan_chunks<<<nb, 256, 0, stream>>>(deg, bsum, rowstart, N, (int)E);

  // fused: csr fill (scatter) overlapped with embed (MFMA) — independent work
  k_embed_fill<<<TP + FB, 256, 0, stream>>>(x, W0b, x0, out_xemb, convTb, x1, N,
                                            src, dstv, rankb, rowstart, csr, E, TP, FB, q8);

  unsigned short* Hb = x0;  // current h (bf16)
  unsigned short* Mb = x1;  // current m (bf16)
  for (int l = 0; l < L; ++l) {
    k_gather<<<TP * 16, 256, 0, stream>>>(csr, rowstart, Mb, x2, N, q8);
    const unsigned short* wTn = (l + 1 < L) ? (convTb + (size_t)(l + 1) * HDIM * HDIM) : nullptr;
    // hnew -> Mb (dead after gather); m_next -> Hb. Final layer: fused readout.
    k_gru_mfma<<<TP, 512, 0, stream>>>(x2, Hb, wIb, wHb, b_ih, b_hh, Mb, wTn, Hb,
                                       lin1_w, lin1_b, out_raw, out_unc, N, q8);
    unsigned short* tmp = Hb; Hb = Mb; Mb = tmp;
  }

  k_graph_reduce<<<256, 256, 0, stream>>>(out_raw, batch, gsum, gcnt, N);
  k_correct<<<(N + 255) / 256, 256, 0, stream>>>(out_raw, batch, gsum, gcnt, out_corrected, N);
}

// Round 11
// 752.221 us; speedup vs baseline: 1.0372x; 1.0372x over previous
//
#include <hip/hip_runtime.h>
#include <hip/hip_bf16.h>

#define HDIM 128
#define FDIM 32
#define GGR  64
#define SCAN_CHUNK 2048
#define FILL_CHUNK 1024
#define FILL_WIN 16

typedef __attribute__((ext_vector_type(8))) short bf16x8;
typedef __attribute__((ext_vector_type(4))) float f32x4;

__device__ __forceinline__ float fsig(float x) {
  return __builtin_amdgcn_rcpf(1.f + __expf(-x));
}
// tanh(x) = 1 - 2/(e^{2x}+1); saturates correctly at +/-inf via rcp(inf)=0.
__device__ __forceinline__ float ftanh(float x) {
  return 1.f - 2.f * __builtin_amdgcn_rcpf(1.f + __expf(2.f * x));
}

__device__ __forceinline__ bf16x8 pack_bf16x8(float4 a, float4 b) {
  union { bf16x8 v; __hip_bfloat162 h[4]; } u;
  u.h[0] = __float22bfloat162_rn(make_float2(a.x, a.y));
  u.h[1] = __float22bfloat162_rn(make_float2(a.z, a.w));
  u.h[2] = __float22bfloat162_rn(make_float2(b.x, b.y));
  u.h[3] = __float22bfloat162_rn(make_float2(b.z, b.w));
  return u.v;
}

// Fragment-order swizzled LDS block index for a 64-row x 128-col bf16 tile.
__device__ __forceinline__ int ablk(int kb, int m) {
  return (kb << 6) + (m & 56) + ((m ^ kb) & 7);
}

__device__ __forceinline__ void stage64(const unsigned short* __restrict__ g,
                                        short* __restrict__ s, int n0, int N, int t) {
#pragma unroll
  for (int r = 0; r < 2; ++r) {
    int idx = r * 512 + t;
    int m = idx >> 4, c8 = idx & 15;
    int gn = n0 + m;
    uint4 v = make_uint4(0u, 0u, 0u, 0u);
    if (gn < N) v = *(const uint4*)(g + (size_t)gn * HDIM + c8 * 8);
    *(uint4*)(s + ablk(c8, m) * 8) = v;
  }
}

// XCD-chunked tile map: physical block p -> logical tile T = (p&7)*q8 + (p>>3).
// Producer and consumer of a node tile land on the same XCD's L2.

// ---------------- fused: CSR histogram (first histBlocks blocks) + embed MFMA ----------------
// hist's per-edge device atomics hide under the embed blocks' MFMA work
// (round-10 lesson: standalone hist is much slower than its fused marginal cost).
__global__ __launch_bounds__(256) void k_embed_hist(const float* __restrict__ x,
                                                    const unsigned short* __restrict__ W0b,
                                                    unsigned short* __restrict__ hb,
                                                    float* __restrict__ xemb,
                                                    const unsigned short* __restrict__ convT0,
                                                    unsigned short* __restrict__ m_out,
                                                    int N,
                                                    const int* __restrict__ dst,
                                                    int* __restrict__ deg,
                                                    unsigned short* __restrict__ rank,
                                                    long long E, int histBlocks, int q8) {
  __shared__ short sE[16 * 64 * 8];
  if ((int)blockIdx.x < histBlocks) {
    long long e = (long long)blockIdx.x * 256 + threadIdx.x;
    if (e < E) {
      int old = atomicAdd(&deg[dst[e]], 1);
      rank[e] = (unsigned short)old;
    }
    return;
  }
  int p = blockIdx.x - histBlocks;
  int T = (p & 7) * q8 + (p >> 3);
  int n0 = T * 64;
  if (n0 >= N) return;
  int t = threadIdx.x;
  int w = t >> 6, l = t & 63;
  int lm = l & 15, lq = l >> 4;
  int j0 = w * 32;
  bf16x8 b0 = *(const bf16x8*)(W0b + (size_t)(j0 + lm) * FDIM + lq * 8);
  bf16x8 b1 = *(const bf16x8*)(W0b + (size_t)(j0 + 16 + lm) * FDIM + lq * 8);
  f32x4 acc0[4], acc1[4];
#pragma unroll
  for (int i = 0; i < 4; ++i) { acc0[i] = (f32x4){0.f,0.f,0.f,0.f}; acc1[i] = (f32x4){0.f,0.f,0.f,0.f}; }
#pragma unroll
  for (int tt = 0; tt < 4; ++tt) {
    int rg = n0 + tt * 16 + lm;
    bf16x8 a = (bf16x8){0,0,0,0,0,0,0,0};
    if (rg < N) {
      const float4* xr = (const float4*)x + (size_t)rg * 8 + lq * 2;
      a = pack_bf16x8(xr[0], xr[1]);
    }
    acc0[tt] = __builtin_amdgcn_mfma_f32_16x16x32_bf16(a, b0, acc0[tt], 0, 0, 0);
    acc1[tt] = __builtin_amdgcn_mfma_f32_16x16x32_bf16(a, b1, acc1[tt], 0, 0, 0);
  }
#pragma unroll
  for (int g = 0; g < 2; ++g) {
    int j = j0 + g * 16 + lm;
#pragma unroll
    for (int tt = 0; tt < 4; ++tt)
#pragma unroll
      for (int r = 0; r < 4; ++r) {
        int m = tt * 16 + lq * 4 + r;
        int node = n0 + m;
        float v = g ? acc1[tt][r] : acc0[tt][r];
        float e = fsig(v);
        __hip_bfloat16 eb = __float2bfloat16(e);
        ((__hip_bfloat16*)sE)[ablk(j >> 3, m) * 8 + (j & 7)] = eb;
        if (node < N) {
          size_t off = (size_t)node * HDIM + j;
          xemb[off] = e;
          ((__hip_bfloat16*)hb)[off] = eb;
        }
      }
  }
  __syncthreads();
  // transform phase: m0 = E @ conv_w[0]  (wT[j][k])
#pragma unroll
  for (int g = 0; g < 2; ++g) {
    int jg = j0 + g * 16;
    f32x4 macc[4];
#pragma unroll
    for (int i = 0; i < 4; ++i) macc[i] = (f32x4){0.f,0.f,0.f,0.f};
#pragma unroll
    for (int ks = 0; ks < 4; ++ks) {
      bf16x8 b = *(const bf16x8*)(convT0 + (size_t)(jg + lm) * HDIM + ks * 32 + lq * 8);
      int kb = ks * 4 + lq;
#pragma unroll
      for (int tt = 0; tt < 4; ++tt) {
        bf16x8 a = *(const bf16x8*)(sE + ablk(kb, tt * 16 + lm) * 8);
        macc[tt] = __builtin_amdgcn_mfma_f32_16x16x32_bf16(a, b, macc[tt], 0, 0, 0);
      }
    }
    int j = jg + lm;
#pragma unroll
    for (int tt = 0; tt < 4; ++tt)
#pragma unroll
      for (int r = 0; r < 4; ++r) {
        int node = n0 + tt * 16 + lq * 4 + r;
        if (node < N)
          ((__hip_bfloat16*)m_out)[(size_t)node * HDIM + j] = __float2bfloat16(macc[tt][r]);
      }
  }
}

// ---------------- weight prep: fp32 -> bf16 (W0, GRU mats, conv transpose) ----------------
__global__ __launch_bounds__(256) void k_prep_w(const float* __restrict__ w_ih,
                                                const float* __restrict__ w_hh,
                                                const float* __restrict__ conv_w,
                                                const float* __restrict__ W0,
                                                unsigned short* __restrict__ wIb,
                                                unsigned short* __restrict__ wHb,
                                                unsigned short* __restrict__ convTb,
                                                unsigned short* __restrict__ W0b,
                                                int L) {
  int i = blockIdx.x * 256 + threadIdx.x;
  if (i < HDIM * FDIM) ((__hip_bfloat16*)W0b)[i] = __float2bfloat16(W0[i]);
  if (i < 384 * HDIM) {
    ((__hip_bfloat16*)wIb)[i] = __float2bfloat16(w_ih[i]);
    ((__hip_bfloat16*)wHb)[i] = __float2bfloat16(w_hh[i]);
  }
  int total = L * HDIM * HDIM;
  if (i < total) {
    int l = i >> 14, rem = i & 16383, j = rem >> 7, k = rem & 127;
    ((__hip_bfloat16*)convTb)[i] = __float2bfloat16(conv_w[(l << 14) + (k << 7) + j]);
  }
}

__global__ __launch_bounds__(256) void k_block_sum(const int* __restrict__ deg,
                                                   int* __restrict__ bsum, int N) {
  int base = blockIdx.x * SCAN_CHUNK + threadIdx.x * 8;
  int s = 0;
#pragma unroll
  for (int u = 0; u < 8; ++u) { int i = base + u; if (i < N) s += deg[i]; }
#pragma unroll
  for (int o = 32; o; o >>= 1) s += __shfl_down(s, o, 64);
  __shared__ int wsum[4];
  if ((threadIdx.x & 63) == 0) wsum[threadIdx.x >> 6] = s;
  __syncthreads();
  if (threadIdx.x == 0) bsum[blockIdx.x] = wsum[0] + wsum[1] + wsum[2] + wsum[3];
}

__global__ void k_scan_bsums(int* __restrict__ bsum, int nb) {
  if (blockIdx.x == 0 && threadIdx.x == 0) {
    int run = 0;
    for (int i = 0; i < nb; ++i) { int v = bsum[i]; bsum[i] = run; run += v; }
  }
}

__global__ __launch_bounds__(256) void k_scan_chunks(const int* __restrict__ deg,
                                                     const int* __restrict__ bsum,
                                                     int* __restrict__ rowstart,
                                                     int N, int Etot) {
  __shared__ int ts[256];
  int base = blockIdx.x * SCAN_CHUNK + threadIdx.x * 8;
  int loc[8]; int s = 0;
#pragma unroll
  for (int u = 0; u < 8; ++u) {
    int i = base + u; loc[u] = s;
    s += (i < N) ? deg[i] : 0;
  }
  ts[threadIdx.x] = s;
  __syncthreads();
  for (int o = 1; o < 256; o <<= 1) {
    int v = (threadIdx.x >= o) ? ts[threadIdx.x - o] : 0;
    __syncthreads();
    ts[threadIdx.x] += v;
    __syncthreads();
  }
  int texcl = (threadIdx.x ? ts[threadIdx.x - 1] : 0) + bsum[blockIdx.x];
#pragma unroll
  for (int u = 0; u < 8; ++u) {
    int i = base + u;
    if (i < N) rowstart[i] = texcl + loc[u];
  }
  if (blockIdx.x == 0 && threadIdx.x == 0) rowstart[N] = Etot;
}

// Windowed, atomic-free CSR fill.
__global__ __launch_bounds__(256) void k_csr_fill_win(const int* __restrict__ src,
                                                      const int* __restrict__ dst,
                                                      const unsigned short* __restrict__ rank,
                                                      const int* __restrict__ rowstart,
                                                      int* __restrict__ csr,
                                                      long long E, int N) {
  __shared__ int sd[FILL_CHUNK];
  __shared__ int ss[FILL_CHUNK];
  __shared__ unsigned short sr[FILL_CHUNK];
  long long base = (long long)blockIdx.x * FILL_CHUNK;
  int cnt = (int)((E - base < FILL_CHUNK) ? (E - base) : FILL_CHUNK);
  for (int i = threadIdx.x; i < cnt; i += 256) {
    sd[i] = dst[base + i];
    ss[i] = src[base + i];
    sr[i] = rank[base + i];
  }
  __syncthreads();
  int nw = (N + FILL_WIN - 1) / FILL_WIN;
#pragma unroll 1
  for (int w = 0; w < FILL_WIN; ++w) {
    int lo = w * nw, hi = lo + nw;
    for (int i = threadIdx.x; i < cnt; i += 256) {
      int d = sd[i];
      if (d >= lo && d < hi)
        csr[rowstart[d] + sr[i]] = ss[i];
    }
    __syncthreads();
  }
}

// ---------------- agg[n] = sum_{row n} m[src]; wave/node, 8 edges x 2KB in flight ----------------
__global__ __launch_bounds__(256) void k_gather(const int* __restrict__ csr,
                                                const int* __restrict__ rowstart,
                                                const unsigned short* __restrict__ m,
                                                unsigned short* __restrict__ agg, int N, int q8) {
  int p = blockIdx.x;
  int G = (p & 7) * q8 * 16 + (p >> 3);
  int wv = threadIdx.x >> 6, l = threadIdx.x & 63;
  int n = G * 4 + wv;
  if (n >= N) return;
  int eq = l >> 3;      // edge slot 0..7
  int jb = l & 7;       // channel group (16 chans, 32B)
  int beg = rowstart[n], end = rowstart[n + 1];
  float acc[16];
#pragma unroll
  for (int i = 0; i < 16; ++i) acc[i] = 0.f;
  for (int e0 = beg; e0 < end; e0 += 8) {
    int e = e0 + eq;
    uint4 v0 = make_uint4(0u, 0u, 0u, 0u);
    uint4 v1 = make_uint4(0u, 0u, 0u, 0u);
    if (e < end) {
      int s = csr[e];
      const uint4* row = (const uint4*)(m + (size_t)s * HDIM + jb * 16);
      v0 = row[0];
      v1 = row[1];
    }
    acc[0]  += __uint_as_float(v0.x << 16);
    acc[1]  += __uint_as_float(v0.x & 0xffff0000u);
    acc[2]  += __uint_as_float(v0.y << 16);
    acc[3]  += __uint_as_float(v0.y & 0xffff0000u);
    acc[4]  += __uint_as_float(v0.z << 16);
    acc[5]  += __uint_as_float(v0.z & 0xffff0000u);
    acc[6]  += __uint_as_float(v0.w << 16);
    acc[7]  += __uint_as_float(v0.w & 0xffff0000u);
    acc[8]  += __uint_as_float(v1.x << 16);
    acc[9]  += __uint_as_float(v1.x & 0xffff0000u);
    acc[10] += __uint_as_float(v1.y << 16);
    acc[11] += __uint_as_float(v1.y & 0xffff0000u);
    acc[12] += __uint_as_float(v1.z << 16);
    acc[13] += __uint_as_float(v1.z & 0xffff0000u);
    acc[14] += __uint_as_float(v1.w << 16);
    acc[15] += __uint_as_float(v1.w & 0xffff0000u);
  }
#pragma unroll
  for (int i = 0; i < 16; ++i) {
    acc[i] += __shfl_xor(acc[i], 8, 64);
    acc[i] += __shfl_xor(acc[i], 16, 64);
    acc[i] += __shfl_xor(acc[i], 32, 64);
  }
  if (eq == 0) {
    union { uint4 v[2]; __hip_bfloat162 h[8]; } o;
#pragma unroll
    for (int i = 0; i < 8; ++i)
      o.h[i] = __float22bfloat162_rn(make_float2(acc[2 * i], acc[2 * i + 1]));
    uint4* dstp = (uint4*)(agg + (size_t)n * HDIM + jb * 16);
    dstp[0] = o.v[0];
    dstp[1] = o.v[1];
  }
}

// ---------------- fused GRU: MFMA gi/gh + elementwise + next transform OR readout ----------------
// Round-5 core (untouchable schedule). Final layer (wT==nullptr): fused readout
// replaces the h_new write: part = relu(hn)*w1[j], 4-step shfl reduce over the
// 16-lane lm group, LDS-atomic into a 64-float tile, write out_raw/out_unc.
__global__ __launch_bounds__(512, 4) void k_gru_mfma(const unsigned short* __restrict__ aggb,
                                                  const unsigned short* __restrict__ hb,
                                                  const unsigned short* __restrict__ wI,
                                                  const unsigned short* __restrict__ wH,
                                                  const float* __restrict__ b_ih,
                                                  const float* __restrict__ b_hh,
                                                  unsigned short* __restrict__ hnewb,
                                                  const unsigned short* __restrict__ wT,
                                                  unsigned short* __restrict__ m_out,
                                                  const float* __restrict__ w1,
                                                  const float* __restrict__ b1,
                                                  float* __restrict__ out_raw,
                                                  float* __restrict__ out_unc,
                                                  int N, int q8) {
  __shared__ short sAg[16 * 64 * 8];
  __shared__ short sH[16 * 64 * 8];
  __shared__ float sOut[64];
  int p = blockIdx.x;
  int T = (p & 7) * q8 + (p >> 3);
  int n0 = T * 64;
  if (n0 >= N) return;
  int t = threadIdx.x;
  stage64(aggb, sAg, n0, N, t);
  stage64(hb, sH, n0, N, t);
  if (!wT && t < 64) sOut[t] = 0.f;
  int w = t >> 6, l = t & 63;
  int j0 = w * 16;
  int lm = l & 15, lq = l >> 4;
  int j = j0 + lm;
  float bir = b_ih[j], biz = b_ih[j + 128], bin = b_ih[j + 256];
  float bhr = b_hh[j], bhz = b_hh[j + 128], bhn = b_hh[j + 256];
  float w1j = 0.f;
  if (!wT) w1j = w1[j];
  __syncthreads();
  f32x4 aR[4], aZ[4], aNi[4], aNh[4];
#pragma unroll
  for (int i = 0; i < 4; ++i) {
    aR[i] = (f32x4){0.f,0.f,0.f,0.f}; aZ[i] = (f32x4){0.f,0.f,0.f,0.f};
    aNi[i] = (f32x4){0.f,0.f,0.f,0.f}; aNh[i] = (f32x4){0.f,0.f,0.f,0.f};
  }
#pragma unroll
  for (int ks = 0; ks < 4; ++ks) {
    size_t rI = (size_t)(j0 + lm) * HDIM + ks * 32 + lq * 8;
    bf16x8 bIr = *(const bf16x8*)(wI + rI);
    bf16x8 bIz = *(const bf16x8*)(wI + rI + 128 * HDIM);
    bf16x8 bIn = *(const bf16x8*)(wI + rI + 256 * HDIM);
    bf16x8 bHr = *(const bf16x8*)(wH + rI);
    bf16x8 bHz = *(const bf16x8*)(wH + rI + 128 * HDIM);
    bf16x8 bHn = *(const bf16x8*)(wH + rI + 256 * HDIM);
    int kb = ks * 4 + lq;
#pragma unroll
    for (int tt = 0; tt < 4; ++tt) {
      bf16x8 a = *(const bf16x8*)(sAg + ablk(kb, tt * 16 + lm) * 8);
      bf16x8 h = *(const bf16x8*)(sH + ablk(kb, tt * 16 + lm) * 8);
      aR[tt] = __builtin_amdgcn_mfma_f32_16x16x32_bf16(a, bIr, aR[tt], 0, 0, 0);
      aR[tt] = __builtin_amdgcn_mfma_f32_16x16x32_bf16(h, bHr, aR[tt], 0, 0, 0);
      aZ[tt] = __builtin_amdgcn_mfma_f32_16x16x32_bf16(a, bIz, aZ[tt], 0, 0, 0);
      aZ[tt] = __builtin_amdgcn_mfma_f32_16x16x32_bf16(h, bHz, aZ[tt], 0, 0, 0);
      aNi[tt] = __builtin_amdgcn_mfma_f32_16x16x32_bf16(a, bIn, aNi[tt], 0, 0, 0);
      aNh[tt] = __builtin_amdgcn_mfma_f32_16x16x32_bf16(h, bHn, aNh[tt], 0, 0, 0);
    }
  }
  // all waves must finish reading sAg before it is reused as the h_new tile
  __syncthreads();
#pragma unroll
  for (int tt = 0; tt < 4; ++tt)
#pragma unroll
    for (int r = 0; r < 4; ++r) {
      int m = tt * 16 + lq * 4 + r;
      int node = n0 + m;
      float hp = __bfloat162float(((const __hip_bfloat16*)sH)[ablk(j >> 3, m) * 8 + (j & 7)]);
      float rg = fsig(aR[tt][r] + bir + bhr);
      float zg = fsig(aZ[tt][r] + biz + bhz);
      float nv = aNi[tt][r] + bin + rg * (aNh[tt][r] + bhn);
      float th = ftanh(nv);
      float hn = (1.f - zg) * th + zg * hp;
      if (wT) {
        __hip_bfloat16 hnb = __float2bfloat16(hn);
        ((__hip_bfloat16*)sAg)[ablk(j >> 3, m) * 8 + (j & 7)] = hnb;
        if (node < N)
          ((__hip_bfloat16*)hnewb)[(size_t)node * HDIM + j] = hnb;
      } else {
        float prt = (node < N) ? fmaxf(hn, 0.f) * w1j : 0.f;
        prt += __shfl_xor(prt, 1, 64);
        prt += __shfl_xor(prt, 2, 64);
        prt += __shfl_xor(prt, 4, 64);
        prt += __shfl_xor(prt, 8, 64);
        if (lm == 0) atomicAdd(&sOut[m], prt);
      }
    }
  if (wT) {
    __syncthreads();
    // m_next = h_new @ conv_w[l+1] straight from the LDS tile
    f32x4 macc[4];
#pragma unroll
    for (int i = 0; i < 4; ++i) macc[i] = (f32x4){0.f,0.f,0.f,0.f};
#pragma unroll
    for (int ks = 0; ks < 4; ++ks) {
      bf16x8 b = *(const bf16x8*)(wT + (size_t)(j0 + lm) * HDIM + ks * 32 + lq * 8);
      int kb = ks * 4 + lq;
#pragma unroll
      for (int tt = 0; tt < 4; ++tt) {
        bf16x8 a = *(const bf16x8*)(sAg + ablk(kb, tt * 16 + lm) * 8);
        macc[tt] = __builtin_amdgcn_mfma_f32_16x16x32_bf16(a, b, macc[tt], 0, 0, 0);
      }
    }
#pragma unroll
    for (int tt = 0; tt < 4; ++tt)
#pragma unroll
      for (int r = 0; r < 4; ++r) {
        int node = n0 + tt * 16 + lq * 4 + r;
        if (node < N)
          ((__hip_bfloat16*)m_out)[(size_t)node * HDIM + j] = __float2bfloat16(macc[tt][r]);
      }
  } else {
    __syncthreads();
    if (t < 64) {
      int node = n0 + t;
      if (node < N) {
        float o = sOut[t] + b1[0];
        out_raw[node] = o;
        out_unc[node] = o;
      }
    }
  }
}

__global__ __launch_bounds__(256) void k_graph_reduce(const float* __restrict__ out_raw,
                                                      const int* __restrict__ batch,
                                                      float* __restrict__ gsum,
                                                      float* __restrict__ gcnt,
                                                      int N) {
  __shared__ float ls[GGR], lc[GGR];
  int t = threadIdx.x;
  if (t < GGR) { ls[t] = 0.f; lc[t] = 0.f; }
  __syncthreads();
  for (int n = blockIdx.x * 256 + t; n < N; n += gridDim.x * 256) {
    int g = batch[n];
    atomicAdd(&ls[g], out_raw[n]);
    atomicAdd(&lc[g], 1.f);
  }
  __syncthreads();
  if (t < GGR) {
    unsafeAtomicAdd(&gsum[t], ls[t]);
    unsafeAtomicAdd(&gcnt[t], lc[t]);
  }
}

__global__ __launch_bounds__(256) void k_correct(const float* __restrict__ out_raw,
                                                 const int* __restrict__ batch,
                                                 const float* __restrict__ gsum,
                                                 const float* __restrict__ gcnt,
                                                 float* __restrict__ corrected, int N) {
  int n = blockIdx.x * 256 + threadIdx.x;
  if (n < N) {
    int g = batch[n];
    corrected[n] = out_raw[n] - gsum[g] / fmaxf(gcnt[g], 1.f);
  }
}

extern "C" void kernel_launch(void* const* d_in, const int* in_sizes, int n_in,
                              void* d_out, int out_size, void* d_ws, size_t ws_size,
                              hipStream_t stream) {
  const float* x      = (const float*)d_in[0];
  const int*   ei     = (const int*)d_in[1];
  const int*   batch  = (const int*)d_in[2];
  const float* W0     = (const float*)d_in[4];
  const float* conv_w = (const float*)d_in[5];
  const float* w_ih   = (const float*)d_in[6];
  const float* b_ih   = (const float*)d_in[7];
  const float* w_hh   = (const float*)d_in[8];
  const float* b_hh   = (const float*)d_in[9];
  const float* lin1_w = (const float*)d_in[10];
  const float* lin1_b = (const float*)d_in[11];

  int N = in_sizes[0] / FDIM;
  long long E = in_sizes[1] / 2;
  int L = in_sizes[5] / (HDIM * HDIM);

  const int* src = ei;
  const int* dstv = ei + E;

  float* out_corrected = (float*)d_out;
  float* out_xemb = out_corrected + N;
  float* out_unc  = out_xemb + (size_t)N * HDIM;

  char* p = (char*)d_ws;
  unsigned short* x0 = (unsigned short*)p; p += (size_t)N * HDIM * 2;
  unsigned short* x1 = (unsigned short*)p; p += (size_t)N * HDIM * 2;
  unsigned short* x2 = (unsigned short*)p; p += (size_t)N * HDIM * 2;
  float* out_raw = (float*)p;        p += (size_t)((N + 3) & ~3) * 4;
  float* gsum = (float*)p;           p += GGR * 4;
  float* gcnt = (float*)p;           p += GGR * 4;
  int* deg = (int*)p;                p += (size_t)((N + 3) & ~3) * 4;
  int* rowstart = (int*)p;           p += (size_t)(N + 4) * 4;
  int nb = (N + SCAN_CHUNK - 1) / SCAN_CHUNK;
  int* bsum = (int*)p;               p += (size_t)((nb + 63) & ~63) * 4;
  int* csr = (int*)p;                p += (size_t)E * 4;
  unsigned short* rankb = (unsigned short*)p;  p += (size_t)((E + 3) & ~3) * 2;
  unsigned short* wIb = (unsigned short*)p;    p += 384 * HDIM * 2;
  unsigned short* wHb = (unsigned short*)p;    p += 384 * HDIM * 2;
  unsigned short* convTb = (unsigned short*)p; p += (size_t)L * HDIM * HDIM * 2;
  unsigned short* W0b = (unsigned short*)p;

  int prep_total = (384 * HDIM > L * HDIM * HDIM) ? 384 * HDIM : L * HDIM * HDIM;
  k_prep_w<<<(prep_total + 255) / 256, 256, 0, stream>>>(w_ih, w_hh, conv_w, W0, wIb, wHb, convTb, W0b, L);

  hipMemsetAsync(deg, 0, (size_t)N * sizeof(int), stream);
  hipMemsetAsync(gsum, 0, 2 * GGR * sizeof(float), stream);

  int nblk = (N + 63) / 64;
  int TP = (nblk + 7) & ~7;   // tile count padded to multiple of 8 XCDs
  int q8 = TP / 8;
  int histBlocks = (int)((E + 255) / 256);
  // fused: hist (scatter atomics) overlapped with embed (MFMA) in one launch
  k_embed_hist<<<histBlocks + TP, 256, 0, stream>>>(x, W0b, x0, out_xemb, convTb, x1, N,
                                                    dstv, deg, rankb, E, histBlocks, q8);

  k_block_sum<<<nb, 256, 0, stream>>>(deg, bsum, N);
  k_scan_bsums<<<1, 64, 0, stream>>>(bsum, nb);
  k_scan_chunks<<<nb, 256, 0, stream>>>(deg, bsum, rowstart, N, (int)E);
  k_csr_fill_win<<<(int)((E + FILL_CHUNK - 1) / FILL_CHUNK), 256, 0, stream>>>(
      src, dstv, rankb, rowstart, csr, E, N);

  unsigned short* Hb = x0;  // current h (bf16)
  unsigned short* Mb = x1;  // current m (bf16)
  for (int l = 0; l < L; ++l) {
    k_gather<<<TP * 16, 256, 0, stream>>>(csr, rowstart, Mb, x2, N, q8);
    const unsigned short* wTn = (l + 1 < L) ? (convTb + (size_t)(l + 1) * HDIM * HDIM) : nullptr;
    // hnew -> Mb (dead after gather); m_next -> Hb. Final layer: fused readout.
    k_gru_mfma<<<TP, 512, 0, stream>>>(x2, Hb, wIb, wHb, b_ih, b_hh, Mb, wTn, Hb,
                                       lin1_w, lin1_b, out_raw, out_unc, N, q8);
    unsigned short* tmp = Hb; Hb = Mb; Mb = tmp;
  }

  k_graph_reduce<<<256, 256, 0, stream>>>(out_raw, batch, gsum, gcnt, N);
  k_correct<<<(N + 255) / 256, 256, 0, stream>>>(out_raw, batch, gsum, gcnt, out_corrected, N);
}

// Round 12
// 731.745 us; speedup vs baseline: 1.0662x; 1.0280x over previous
//
#include <hip/hip_runtime.h>
#include <hip/hip_bf16.h>

#define HDIM 128
#define FDIM 32
#define GGR  64
#define SCAN_CHUNK 2048
#define FILL_CHUNK 1024
#define FILL_WIN 16

typedef __attribute__((ext_vector_type(8))) short bf16x8;
typedef __attribute__((ext_vector_type(4))) float f32x4;

__device__ __forceinline__ float fsig(float x) {
  return __builtin_amdgcn_rcpf(1.f + __expf(-x));
}
// tanh(x) = 1 - 2/(e^{2x}+1); saturates correctly at +/-inf via rcp(inf)=0.
__device__ __forceinline__ float ftanh(float x) {
  return 1.f - 2.f * __builtin_amdgcn_rcpf(1.f + __expf(2.f * x));
}

__device__ __forceinline__ bf16x8 pack_bf16x8(float4 a, float4 b) {
  union { bf16x8 v; __hip_bfloat162 h[4]; } u;
  u.h[0] = __float22bfloat162_rn(make_float2(a.x, a.y));
  u.h[1] = __float22bfloat162_rn(make_float2(a.z, a.w));
  u.h[2] = __float22bfloat162_rn(make_float2(b.x, b.y));
  u.h[3] = __float22bfloat162_rn(make_float2(b.z, b.w));
  return u.v;
}

// Fragment-order swizzled LDS block index for a 64-row x 128-col bf16 tile.
__device__ __forceinline__ int ablk(int kb, int m) {
  return (kb << 6) + (m & 56) + ((m ^ kb) & 7);
}

__device__ __forceinline__ void stage64(const unsigned short* __restrict__ g,
                                        short* __restrict__ s, int n0, int N, int t) {
#pragma unroll
  for (int r = 0; r < 2; ++r) {
    int idx = r * 512 + t;
    int m = idx >> 4, c8 = idx & 15;
    int gn = n0 + m;
    uint4 v = make_uint4(0u, 0u, 0u, 0u);
    if (gn < N) v = *(const uint4*)(g + (size_t)gn * HDIM + c8 * 8);
    *(uint4*)(s + ablk(c8, m) * 8) = v;
  }
}

// XCD-chunked tile map: physical block p -> logical tile T = (p&7)*q8 + (p>>3).

// ---------------- fused: CSR histogram (first histBlocks blocks) + embed MFMA ----------------
__global__ __launch_bounds__(256) void k_embed_hist(const float* __restrict__ x,
                                                    const unsigned short* __restrict__ W0b,
                                                    unsigned short* __restrict__ hb,
                                                    float* __restrict__ xemb,
                                                    const unsigned short* __restrict__ convT0,
                                                    unsigned short* __restrict__ m_out,
                                                    int N,
                                                    const int* __restrict__ dst,
                                                    int* __restrict__ deg,
                                                    unsigned short* __restrict__ rank,
                                                    long long E, int histBlocks, int q8) {
  __shared__ short sE[16 * 64 * 8];
  if ((int)blockIdx.x < histBlocks) {
    long long e = (long long)blockIdx.x * 256 + threadIdx.x;
    if (e < E) {
      int old = atomicAdd(&deg[dst[e]], 1);
      rank[e] = (unsigned short)old;
    }
    return;
  }
  int p = blockIdx.x - histBlocks;
  int T = (p & 7) * q8 + (p >> 3);
  int n0 = T * 64;
  if (n0 >= N) return;
  int t = threadIdx.x;
  int w = t >> 6, l = t & 63;
  int lm = l & 15, lq = l >> 4;
  int j0 = w * 32;
  bf16x8 b0 = *(const bf16x8*)(W0b + (size_t)(j0 + lm) * FDIM + lq * 8);
  bf16x8 b1 = *(const bf16x8*)(W0b + (size_t)(j0 + 16 + lm) * FDIM + lq * 8);
  f32x4 acc0[4], acc1[4];
#pragma unroll
  for (int i = 0; i < 4; ++i) { acc0[i] = (f32x4){0.f,0.f,0.f,0.f}; acc1[i] = (f32x4){0.f,0.f,0.f,0.f}; }
#pragma unroll
  for (int tt = 0; tt < 4; ++tt) {
    int rg = n0 + tt * 16 + lm;
    bf16x8 a = (bf16x8){0,0,0,0,0,0,0,0};
    if (rg < N) {
      const float4* xr = (const float4*)x + (size_t)rg * 8 + lq * 2;
      a = pack_bf16x8(xr[0], xr[1]);
    }
    acc0[tt] = __builtin_amdgcn_mfma_f32_16x16x32_bf16(a, b0, acc0[tt], 0, 0, 0);
    acc1[tt] = __builtin_amdgcn_mfma_f32_16x16x32_bf16(a, b1, acc1[tt], 0, 0, 0);
  }
#pragma unroll
  for (int g = 0; g < 2; ++g) {
    int j = j0 + g * 16 + lm;
#pragma unroll
    for (int tt = 0; tt < 4; ++tt)
#pragma unroll
      for (int r = 0; r < 4; ++r) {
        int m = tt * 16 + lq * 4 + r;
        int node = n0 + m;
        float v = g ? acc1[tt][r] : acc0[tt][r];
        float e = fsig(v);
        __hip_bfloat16 eb = __float2bfloat16(e);
        ((__hip_bfloat16*)sE)[ablk(j >> 3, m) * 8 + (j & 7)] = eb;
        if (node < N) {
          size_t off = (size_t)node * HDIM + j;
          xemb[off] = e;
          ((__hip_bfloat16*)hb)[off] = eb;
        }
      }
  }
  __syncthreads();
  // transform phase: m0 = E @ conv_w[0]  (wT[j][k])
#pragma unroll
  for (int g = 0; g < 2; ++g) {
    int jg = j0 + g * 16;
    f32x4 macc[4];
#pragma unroll
    for (int i = 0; i < 4; ++i) macc[i] = (f32x4){0.f,0.f,0.f,0.f};
#pragma unroll
    for (int ks = 0; ks < 4; ++ks) {
      bf16x8 b = *(const bf16x8*)(convT0 + (size_t)(jg + lm) * HDIM + ks * 32 + lq * 8);
      int kb = ks * 4 + lq;
#pragma unroll
      for (int tt = 0; tt < 4; ++tt) {
        bf16x8 a = *(const bf16x8*)(sE + ablk(kb, tt * 16 + lm) * 8);
        macc[tt] = __builtin_amdgcn_mfma_f32_16x16x32_bf16(a, b, macc[tt], 0, 0, 0);
      }
    }
    int j = jg + lm;
#pragma unroll
    for (int tt = 0; tt < 4; ++tt)
#pragma unroll
      for (int r = 0; r < 4; ++r) {
        int node = n0 + tt * 16 + lq * 4 + r;
        if (node < N)
          ((__hip_bfloat16*)m_out)[(size_t)node * HDIM + j] = __float2bfloat16(macc[tt][r]);
      }
  }
}

// ---------------- weight prep: fp32 -> bf16 (W0, GRU mats, conv transpose) ----------------
__global__ __launch_bounds__(256) void k_prep_w(const float* __restrict__ w_ih,
                                                const float* __restrict__ w_hh,
                                                const float* __restrict__ conv_w,
                                                const float* __restrict__ W0,
                                                unsigned short* __restrict__ wIb,
                                                unsigned short* __restrict__ wHb,
                                                unsigned short* __restrict__ convTb,
                                                unsigned short* __restrict__ W0b,
                                                int L) {
  int i = blockIdx.x * 256 + threadIdx.x;
  if (i < HDIM * FDIM) ((__hip_bfloat16*)W0b)[i] = __float2bfloat16(W0[i]);
  if (i < 384 * HDIM) {
    ((__hip_bfloat16*)wIb)[i] = __float2bfloat16(w_ih[i]);
    ((__hip_bfloat16*)wHb)[i] = __float2bfloat16(w_hh[i]);
  }
  int total = L * HDIM * HDIM;
  if (i < total) {
    int l = i >> 14, rem = i & 16383, j = rem >> 7, k = rem & 127;
    ((__hip_bfloat16*)convTb)[i] = __float2bfloat16(conv_w[(l << 14) + (k << 7) + j]);
  }
}

__global__ __launch_bounds__(256) void k_block_sum(const int* __restrict__ deg,
                                                   int* __restrict__ bsum, int N) {
  int base = blockIdx.x * SCAN_CHUNK + threadIdx.x * 8;
  int s = 0;
#pragma unroll
  for (int u = 0; u < 8; ++u) { int i = base + u; if (i < N) s += deg[i]; }
#pragma unroll
  for (int o = 32; o; o >>= 1) s += __shfl_down(s, o, 64);
  __shared__ int wsum[4];
  if ((threadIdx.x & 63) == 0) wsum[threadIdx.x >> 6] = s;
  __syncthreads();
  if (threadIdx.x == 0) bsum[blockIdx.x] = wsum[0] + wsum[1] + wsum[2] + wsum[3];
}

__global__ void k_scan_bsums(int* __restrict__ bsum, int nb) {
  if (blockIdx.x == 0 && threadIdx.x == 0) {
    int run = 0;
    for (int i = 0; i < nb; ++i) { int v = bsum[i]; bsum[i] = run; run += v; }
  }
}

__global__ __launch_bounds__(256) void k_scan_chunks(const int* __restrict__ deg,
                                                     const int* __restrict__ bsum,
                                                     int* __restrict__ rowstart,
                                                     int N, int Etot) {
  __shared__ int ts[256];
  int base = blockIdx.x * SCAN_CHUNK + threadIdx.x * 8;
  int loc[8]; int s = 0;
#pragma unroll
  for (int u = 0; u < 8; ++u) {
    int i = base + u; loc[u] = s;
    s += (i < N) ? deg[i] : 0;
  }
  ts[threadIdx.x] = s;
  __syncthreads();
  for (int o = 1; o < 256; o <<= 1) {
    int v = (threadIdx.x >= o) ? ts[threadIdx.x - o] : 0;
    __syncthreads();
    ts[threadIdx.x] += v;
    __syncthreads();
  }
  int texcl = (threadIdx.x ? ts[threadIdx.x - 1] : 0) + bsum[blockIdx.x];
#pragma unroll
  for (int u = 0; u < 8; ++u) {
    int i = base + u;
    if (i < N) rowstart[i] = texcl + loc[u];
  }
  if (blockIdx.x == 0 && threadIdx.x == 0) rowstart[N] = Etot;
}

// Windowed, atomic-free CSR fill.
__global__ __launch_bounds__(256) void k_csr_fill_win(const int* __restrict__ src,
                                                      const int* __restrict__ dst,
                                                      const unsigned short* __restrict__ rank,
                                                      const int* __restrict__ rowstart,
                                                      int* __restrict__ csr,
                                                      long long E, int N) {
  __shared__ int sd[FILL_CHUNK];
  __shared__ int ss[FILL_CHUNK];
  __shared__ unsigned short sr[FILL_CHUNK];
  long long base = (long long)blockIdx.x * FILL_CHUNK;
  int cnt = (int)((E - base < FILL_CHUNK) ? (E - base) : FILL_CHUNK);
  for (int i = threadIdx.x; i < cnt; i += 256) {
    sd[i] = dst[base + i];
    ss[i] = src[base + i];
    sr[i] = rank[base + i];
  }
  __syncthreads();
  int nw = (N + FILL_WIN - 1) / FILL_WIN;
#pragma unroll 1
  for (int w = 0; w < FILL_WIN; ++w) {
    int lo = w * nw, hi = lo + nw;
    for (int i = threadIdx.x; i < cnt; i += 256) {
      int d = sd[i];
      if (d >= lo && d < hi)
        csr[rowstart[d] + sr[i]] = ss[i];
    }
    __syncthreads();
  }
}

// ---------------- agg[n] = sum_{row n} m[src]; wave/node, 8 edges x 2KB in flight ----------------
__global__ __launch_bounds__(256) void k_gather(const int* __restrict__ csr,
                                                const int* __restrict__ rowstart,
                                                const unsigned short* __restrict__ m,
                                                unsigned short* __restrict__ agg, int N, int q8) {
  int p = blockIdx.x;
  int G = (p & 7) * q8 * 16 + (p >> 3);
  int wv = threadIdx.x >> 6, l = threadIdx.x & 63;
  int n = G * 4 + wv;
  if (n >= N) return;
  int eq = l >> 3;      // edge slot 0..7
  int jb = l & 7;       // channel group (16 chans, 32B)
  int beg = rowstart[n], end = rowstart[n + 1];
  float acc[16];
#pragma unroll
  for (int i = 0; i < 16; ++i) acc[i] = 0.f;
  for (int e0 = beg; e0 < end; e0 += 8) {
    int e = e0 + eq;
    uint4 v0 = make_uint4(0u, 0u, 0u, 0u);
    uint4 v1 = make_uint4(0u, 0u, 0u, 0u);
    if (e < end) {
      int s = csr[e];
      const uint4* row = (const uint4*)(m + (size_t)s * HDIM + jb * 16);
      v0 = row[0];
      v1 = row[1];
    }
    acc[0]  += __uint_as_float(v0.x << 16);
    acc[1]  += __uint_as_float(v0.x & 0xffff0000u);
    acc[2]  += __uint_as_float(v0.y << 16);
    acc[3]  += __uint_as_float(v0.y & 0xffff0000u);
    acc[4]  += __uint_as_float(v0.z << 16);
    acc[5]  += __uint_as_float(v0.z & 0xffff0000u);
    acc[6]  += __uint_as_float(v0.w << 16);
    acc[7]  += __uint_as_float(v0.w & 0xffff0000u);
    acc[8]  += __uint_as_float(v1.x << 16);
    acc[9]  += __uint_as_float(v1.x & 0xffff0000u);
    acc[10] += __uint_as_float(v1.y << 16);
    acc[11] += __uint_as_float(v1.y & 0xffff0000u);
    acc[12] += __uint_as_float(v1.z << 16);
    acc[13] += __uint_as_float(v1.z & 0xffff0000u);
    acc[14] += __uint_as_float(v1.w << 16);
    acc[15] += __uint_as_float(v1.w & 0xffff0000u);
  }
#pragma unroll
  for (int i = 0; i < 16; ++i) {
    acc[i] += __shfl_xor(acc[i], 8, 64);
    acc[i] += __shfl_xor(acc[i], 16, 64);
    acc[i] += __shfl_xor(acc[i], 32, 64);
  }
  if (eq == 0) {
    union { uint4 v[2]; __hip_bfloat162 h[8]; } o;
#pragma unroll
    for (int i = 0; i < 8; ++i)
      o.h[i] = __float22bfloat162_rn(make_float2(acc[2 * i], acc[2 * i + 1]));
    uint4* dstp = (uint4*)(agg + (size_t)n * HDIM + jb * 16);
    dstp[0] = o.v[0];
    dstp[1] = o.v[1];
  }
}

// ---------------- fused GRU (layers 0..L-2): exact round-9 body ----------------
__global__ __launch_bounds__(512, 4) void k_gru_mfma(const unsigned short* __restrict__ aggb,
                                                  const unsigned short* __restrict__ hb,
                                                  const unsigned short* __restrict__ wI,
                                                  const unsigned short* __restrict__ wH,
                                                  const float* __restrict__ b_ih,
                                                  const float* __restrict__ b_hh,
                                                  unsigned short* __restrict__ hnewb,
                                                  const unsigned short* __restrict__ wT,
                                                  unsigned short* __restrict__ m_out,
                                                  int N, int q8) {
  __shared__ short sAg[16 * 64 * 8];
  __shared__ short sH[16 * 64 * 8];
  int p = blockIdx.x;
  int T = (p & 7) * q8 + (p >> 3);
  int n0 = T * 64;
  if (n0 >= N) return;
  int t = threadIdx.x;
  stage64(aggb, sAg, n0, N, t);
  stage64(hb, sH, n0, N, t);
  int w = t >> 6, l = t & 63;
  int j0 = w * 16;
  int lm = l & 15, lq = l >> 4;
  int j = j0 + lm;
  float bir = b_ih[j], biz = b_ih[j + 128], bin = b_ih[j + 256];
  float bhr = b_hh[j], bhz = b_hh[j + 128], bhn = b_hh[j + 256];
  __syncthreads();
  f32x4 aR[4], aZ[4], aNi[4], aNh[4];
#pragma unroll
  for (int i = 0; i < 4; ++i) {
    aR[i] = (f32x4){0.f,0.f,0.f,0.f}; aZ[i] = (f32x4){0.f,0.f,0.f,0.f};
    aNi[i] = (f32x4){0.f,0.f,0.f,0.f}; aNh[i] = (f32x4){0.f,0.f,0.f,0.f};
  }
#pragma unroll
  for (int ks = 0; ks < 4; ++ks) {
    size_t rI = (size_t)(j0 + lm) * HDIM + ks * 32 + lq * 8;
    bf16x8 bIr = *(const bf16x8*)(wI + rI);
    bf16x8 bIz = *(const bf16x8*)(wI + rI + 128 * HDIM);
    bf16x8 bIn = *(const bf16x8*)(wI + rI + 256 * HDIM);
    bf16x8 bHr = *(const bf16x8*)(wH + rI);
    bf16x8 bHz = *(const bf16x8*)(wH + rI + 128 * HDIM);
    bf16x8 bHn = *(const bf16x8*)(wH + rI + 256 * HDIM);
    int kb = ks * 4 + lq;
#pragma unroll
    for (int tt = 0; tt < 4; ++tt) {
      bf16x8 a = *(const bf16x8*)(sAg + ablk(kb, tt * 16 + lm) * 8);
      bf16x8 h = *(const bf16x8*)(sH + ablk(kb, tt * 16 + lm) * 8);
      aR[tt] = __builtin_amdgcn_mfma_f32_16x16x32_bf16(a, bIr, aR[tt], 0, 0, 0);
      aR[tt] = __builtin_amdgcn_mfma_f32_16x16x32_bf16(h, bHr, aR[tt], 0, 0, 0);
      aZ[tt] = __builtin_amdgcn_mfma_f32_16x16x32_bf16(a, bIz, aZ[tt], 0, 0, 0);
      aZ[tt] = __builtin_amdgcn_mfma_f32_16x16x32_bf16(h, bHz, aZ[tt], 0, 0, 0);
      aNi[tt] = __builtin_amdgcn_mfma_f32_16x16x32_bf16(a, bIn, aNi[tt], 0, 0, 0);
      aNh[tt] = __builtin_amdgcn_mfma_f32_16x16x32_bf16(h, bHn, aNh[tt], 0, 0, 0);
    }
  }
  // all waves must finish reading sAg before it is reused as the h_new tile
  __syncthreads();
#pragma unroll
  for (int tt = 0; tt < 4; ++tt)
#pragma unroll
    for (int r = 0; r < 4; ++r) {
      int m = tt * 16 + lq * 4 + r;
      int node = n0 + m;
      float hp = __bfloat162float(((const __hip_bfloat16*)sH)[ablk(j >> 3, m) * 8 + (j & 7)]);
      float rg = fsig(aR[tt][r] + bir + bhr);
      float zg = fsig(aZ[tt][r] + biz + bhz);
      float nv = aNi[tt][r] + bin + rg * (aNh[tt][r] + bhn);
      float th = ftanh(nv);
      float hn = (1.f - zg) * th + zg * hp;
      __hip_bfloat16 hnb = __float2bfloat16(hn);
      ((__hip_bfloat16*)sAg)[ablk(j >> 3, m) * 8 + (j & 7)] = hnb;
      if (node < N)
        ((__hip_bfloat16*)hnewb)[(size_t)node * HDIM + j] = hnb;
    }
  __syncthreads();
  // m_next = h_new @ conv_w[l+1] straight from the LDS tile
  f32x4 macc[4];
#pragma unroll
  for (int i = 0; i < 4; ++i) macc[i] = (f32x4){0.f,0.f,0.f,0.f};
#pragma unroll
  for (int ks = 0; ks < 4; ++ks) {
    bf16x8 b = *(const bf16x8*)(wT + (size_t)(j0 + lm) * HDIM + ks * 32 + lq * 8);
    int kb = ks * 4 + lq;
#pragma unroll
    for (int tt = 0; tt < 4; ++tt) {
      bf16x8 a = *(const bf16x8*)(sAg + ablk(kb, tt * 16 + lm) * 8);
      macc[tt] = __builtin_amdgcn_mfma_f32_16x16x32_bf16(a, b, macc[tt], 0, 0, 0);
    }
  }
#pragma unroll
  for (int tt = 0; tt < 4; ++tt)
#pragma unroll
    for (int r = 0; r < 4; ++r) {
      int node = n0 + tt * 16 + lq * 4 + r;
      if (node < N)
        ((__hip_bfloat16*)m_out)[(size_t)node * HDIM + j] = __float2bfloat16(macc[tt][r]);
    }
}

// ---------------- final-layer GRU with fused readout (separate instantiation so
// layers 0..L-2 keep the round-9 register allocation) ----------------
__global__ __launch_bounds__(512, 4) void k_gru_last(const unsigned short* __restrict__ aggb,
                                                  const unsigned short* __restrict__ hb,
                                                  const unsigned short* __restrict__ wI,
                                                  const unsigned short* __restrict__ wH,
                                                  const float* __restrict__ b_ih,
                                                  const float* __restrict__ b_hh,
                                                  const float* __restrict__ w1,
                                                  const float* __restrict__ b1,
                                                  float* __restrict__ out_raw,
                                                  float* __restrict__ out_unc,
                                                  int N, int q8) {
  __shared__ short sAg[16 * 64 * 8];
  __shared__ short sH[16 * 64 * 8];
  __shared__ float sOut[64];
  int p = blockIdx.x;
  int T = (p & 7) * q8 + (p >> 3);
  int n0 = T * 64;
  if (n0 >= N) return;
  int t = threadIdx.x;
  stage64(aggb, sAg, n0, N, t);
  stage64(hb, sH, n0, N, t);
  if (t < 64) sOut[t] = 0.f;
  int w = t >> 6, l = t & 63;
  int j0 = w * 16;
  int lm = l & 15, lq = l >> 4;
  int j = j0 + lm;
  float bir = b_ih[j], biz = b_ih[j + 128], bin = b_ih[j + 256];
  float bhr = b_hh[j], bhz = b_hh[j + 128], bhn = b_hh[j + 256];
  float w1j = w1[j];
  __syncthreads();
  f32x4 aR[4], aZ[4], aNi[4], aNh[4];
#pragma unroll
  for (int i = 0; i < 4; ++i) {
    aR[i] = (f32x4){0.f,0.f,0.f,0.f}; aZ[i] = (f32x4){0.f,0.f,0.f,0.f};
    aNi[i] = (f32x4){0.f,0.f,0.f,0.f}; aNh[i] = (f32x4){0.f,0.f,0.f,0.f};
  }
#pragma unroll
  for (int ks = 0; ks < 4; ++ks) {
    size_t rI = (size_t)(j0 + lm) * HDIM + ks * 32 + lq * 8;
    bf16x8 bIr = *(const bf16x8*)(wI + rI);
    bf16x8 bIz = *(const bf16x8*)(wI + rI + 128 * HDIM);
    bf16x8 bIn = *(const bf16x8*)(wI + rI + 256 * HDIM);
    bf16x8 bHr = *(const bf16x8*)(wH + rI);
    bf16x8 bHz = *(const bf16x8*)(wH + rI + 128 * HDIM);
    bf16x8 bHn = *(const bf16x8*)(wH + rI + 256 * HDIM);
    int kb = ks * 4 + lq;
#pragma unroll
    for (int tt = 0; tt < 4; ++tt) {
      bf16x8 a = *(const bf16x8*)(sAg + ablk(kb, tt * 16 + lm) * 8);
      bf16x8 h = *(const bf16x8*)(sH + ablk(kb, tt * 16 + lm) * 8);
      aR[tt] = __builtin_amdgcn_mfma_f32_16x16x32_bf16(a, bIr, aR[tt], 0, 0, 0);
      aR[tt] = __builtin_amdgcn_mfma_f32_16x16x32_bf16(h, bHr, aR[tt], 0, 0, 0);
      aZ[tt] = __builtin_amdgcn_mfma_f32_16x16x32_bf16(a, bIz, aZ[tt], 0, 0, 0);
      aZ[tt] = __builtin_amdgcn_mfma_f32_16x16x32_bf16(h, bHz, aZ[tt], 0, 0, 0);
      aNi[tt] = __builtin_amdgcn_mfma_f32_16x16x32_bf16(a, bIn, aNi[tt], 0, 0, 0);
      aNh[tt] = __builtin_amdgcn_mfma_f32_16x16x32_bf16(h, bHn, aNh[tt], 0, 0, 0);
    }
  }
  __syncthreads();
#pragma unroll
  for (int tt = 0; tt < 4; ++tt)
#pragma unroll
    for (int r = 0; r < 4; ++r) {
      int m = tt * 16 + lq * 4 + r;
      int node = n0 + m;
      float hp = __bfloat162float(((const __hip_bfloat16*)sH)[ablk(j >> 3, m) * 8 + (j & 7)]);
      float rg = fsig(aR[tt][r] + bir + bhr);
      float zg = fsig(aZ[tt][r] + biz + bhz);
      float nv = aNi[tt][r] + bin + rg * (aNh[tt][r] + bhn);
      float th = ftanh(nv);
      float hn = (1.f - zg) * th + zg * hp;
      float prt = (node < N) ? fmaxf(hn, 0.f) * w1j : 0.f;
      prt += __shfl_xor(prt, 1, 64);
      prt += __shfl_xor(prt, 2, 64);
      prt += __shfl_xor(prt, 4, 64);
      prt += __shfl_xor(prt, 8, 64);
      if (lm == 0) atomicAdd(&sOut[m], prt);
    }
  __syncthreads();
  if (t < 64) {
    int node = n0 + t;
    if (node < N) {
      float o = sOut[t] + b1[0];
      out_raw[node] = o;
      out_unc[node] = o;
    }
  }
}

__global__ __launch_bounds__(256) void k_graph_reduce(const float* __restrict__ out_raw,
                                                      const int* __restrict__ batch,
                                                      float* __restrict__ gsum,
                                                      float* __restrict__ gcnt,
                                                      int N) {
  __shared__ float ls[GGR], lc[GGR];
  int t = threadIdx.x;
  if (t < GGR) { ls[t] = 0.f; lc[t] = 0.f; }
  __syncthreads();
  for (int n = blockIdx.x * 256 + t; n < N; n += gridDim.x * 256) {
    int g = batch[n];
    atomicAdd(&ls[g], out_raw[n]);
    atomicAdd(&lc[g], 1.f);
  }
  __syncthreads();
  if (t < GGR) {
    unsafeAtomicAdd(&gsum[t], ls[t]);
    unsafeAtomicAdd(&gcnt[t], lc[t]);
  }
}

__global__ __launch_bounds__(256) void k_correct(const float* __restrict__ out_raw,
                                                 const int* __restrict__ batch,
                                                 const float* __restrict__ gsum,
                                                 const float* __restrict__ gcnt,
                                                 float* __restrict__ corrected, int N) {
  int n = blockIdx.x * 256 + threadIdx.x;
  if (n < N) {
    int g = batch[n];
    corrected[n] = out_raw[n] - gsum[g] / fmaxf(gcnt[g], 1.f);
  }
}

extern "C" void kernel_launch(void* const* d_in, const int* in_sizes, int n_in,
                              void* d_out, int out_size, void* d_ws, size_t ws_size,
                              hipStream_t stream) {
  const float* x      = (const float*)d_in[0];
  const int*   ei     = (const int*)d_in[1];
  const int*   batch  = (const int*)d_in[2];
  const float* W0     = (const float*)d_in[4];
  const float* conv_w = (const float*)d_in[5];
  const float* w_ih   = (const float*)d_in[6];
  const float* b_ih   = (const float*)d_in[7];
  const float* w_hh   = (const float*)d_in[8];
  const float* b_hh   = (const float*)d_in[9];
  const float* lin1_w = (const float*)d_in[10];
  const float* lin1_b = (const float*)d_in[11];

  int N = in_sizes[0] / FDIM;
  long long E = in_sizes[1] / 2;
  int L = in_sizes[5] / (HDIM * HDIM);

  const int* src = ei;
  const int* dstv = ei + E;

  float* out_corrected = (float*)d_out;
  float* out_xemb = out_corrected + N;
  float* out_unc  = out_xemb + (size_t)N * HDIM;

  char* p = (char*)d_ws;
  unsigned short* x0 = (unsigned short*)p; p += (size_t)N * HDIM * 2;
  unsigned short* x1 = (unsigned short*)p; p += (size_t)N * HDIM * 2;
  unsigned short* x2 = (unsigned short*)p; p += (size_t)N * HDIM * 2;
  float* out_raw = (float*)p;        p += (size_t)((N + 3) & ~3) * 4;
  float* gsum = (float*)p;           p += GGR * 4;
  float* gcnt = (float*)p;           p += GGR * 4;
  int* deg = (int*)p;                p += (size_t)((N + 3) & ~3) * 4;
  int* rowstart = (int*)p;           p += (size_t)(N + 4) * 4;
  int nb = (N + SCAN_CHUNK - 1) / SCAN_CHUNK;
  int* bsum = (int*)p;               p += (size_t)((nb + 63) & ~63) * 4;
  int* csr = (int*)p;                p += (size_t)E * 4;
  unsigned short* rankb = (unsigned short*)p;  p += (size_t)((E + 3) & ~3) * 2;
  unsigned short* wIb = (unsigned short*)p;    p += 384 * HDIM * 2;
  unsigned short* wHb = (unsigned short*)p;    p += 384 * HDIM * 2;
  unsigned short* convTb = (unsigned short*)p; p += (size_t)L * HDIM * HDIM * 2;
  unsigned short* W0b = (unsigned short*)p;

  int prep_total = (384 * HDIM > L * HDIM * HDIM) ? 384 * HDIM : L * HDIM * HDIM;
  k_prep_w<<<(prep_total + 255) / 256, 256, 0, stream>>>(w_ih, w_hh, conv_w, W0, wIb, wHb, convTb, W0b, L);

  hipMemsetAsync(deg, 0, (size_t)N * sizeof(int), stream);
  hipMemsetAsync(gsum, 0, 2 * GGR * sizeof(float), stream);

  int nblk = (N + 63) / 64;
  int TP = (nblk + 7) & ~7;   // tile count padded to multiple of 8 XCDs
  int q8 = TP / 8;
  int histBlocks = (int)((E + 255) / 256);
  // fused: hist (scatter atomics) overlapped with embed (MFMA) in one launch
  k_embed_hist<<<histBlocks + TP, 256, 0, stream>>>(x, W0b, x0, out_xemb, convTb, x1, N,
                                                    dstv, deg, rankb, E, histBlocks, q8);

  k_block_sum<<<nb, 256, 0, stream>>>(deg, bsum, N);
  k_scan_bsums<<<1, 64, 0, stream>>>(bsum, nb);
  k_scan_chunks<<<nb, 256, 0, stream>>>(deg, bsum, rowstart, N, (int)E);
  k_csr_fill_win<<<(int)((E + FILL_CHUNK - 1) / FILL_CHUNK), 256, 0, stream>>>(
      src, dstv, rankb, rowstart, csr, E, N);

  unsigned short* Hb = x0;  // current h (bf16)
  unsigned short* Mb = x1;  // current m (bf16)
  for (int l = 0; l < L; ++l) {
    k_gather<<<TP * 16, 256, 0, stream>>>(csr, rowstart, Mb, x2, N, q8);
    if (l + 1 < L) {
      const unsigned short* wTn = convTb + (size_t)(l + 1) * HDIM * HDIM;
      // hnew -> Mb (dead after gather); m_next -> Hb (blocks rewrite only their staged rows)
      k_gru_mfma<<<TP, 512, 0, stream>>>(x2, Hb, wIb, wHb, b_ih, b_hh, Mb, wTn, Hb, N, q8);
      unsigned short* tmp = Hb; Hb = Mb; Mb = tmp;
    } else {
      // final layer: fused readout, no h_new/m_next outputs
      k_gru_last<<<TP, 512, 0, stream>>>(x2, Hb, wIb, wHb, b_ih, b_hh,
                                         lin1_w, lin1_b, out_raw, out_unc, N, q8);
    }
  }

  k_graph_reduce<<<256, 256, 0, stream>>>(out_raw, batch, gsum, gcnt, N);
  k_correct<<<(N + 255) / 256, 256, 0, stream>>>(out_raw, batch, gsum, gcnt, out_corrected, N);
}

// Round 13
// 715.512 us; speedup vs baseline: 1.0904x; 1.0227x over previous
//
#include <hip/hip_runtime.h>
#include <hip/hip_bf16.h>

#define HDIM 128
#define FDIM 32
#define GGR  64
#define SCAN_CHUNK 2048
#define FILL_CHUNK 1024
#define FILL_WIN 16

typedef __attribute__((ext_vector_type(8))) short bf16x8;
typedef __attribute__((ext_vector_type(4))) float f32x4;

__device__ __forceinline__ float fsig(float x) {
  return __builtin_amdgcn_rcpf(1.f + __expf(-x));
}
// tanh(x) = 1 - 2/(e^{2x}+1); saturates correctly at +/-inf via rcp(inf)=0.
__device__ __forceinline__ float ftanh(float x) {
  return 1.f - 2.f * __builtin_amdgcn_rcpf(1.f + __expf(2.f * x));
}

__device__ __forceinline__ bf16x8 pack_bf16x8(float4 a, float4 b) {
  union { bf16x8 v; __hip_bfloat162 h[4]; } u;
  u.h[0] = __float22bfloat162_rn(make_float2(a.x, a.y));
  u.h[1] = __float22bfloat162_rn(make_float2(a.z, a.w));
  u.h[2] = __float22bfloat162_rn(make_float2(b.x, b.y));
  u.h[3] = __float22bfloat162_rn(make_float2(b.z, b.w));
  return u.v;
}

// Fragment-order swizzled LDS block index for a 64-row x 128-col bf16 tile.
__device__ __forceinline__ int ablk(int kb, int m) {
  return (kb << 6) + (m & 56) + ((m ^ kb) & 7);
}

__device__ __forceinline__ void stage64(const unsigned short* __restrict__ g,
                                        short* __restrict__ s, int n0, int N, int t) {
#pragma unroll
  for (int r = 0; r < 2; ++r) {
    int idx = r * 512 + t;
    int m = idx >> 4, c8 = idx & 15;
    int gn = n0 + m;
    uint4 v = make_uint4(0u, 0u, 0u, 0u);
    if (gn < N) v = *(const uint4*)(g + (size_t)gn * HDIM + c8 * 8);
    *(uint4*)(s + ablk(c8, m) * 8) = v;
  }
}

// XCD-chunked tile map: physical block p -> logical tile T = (p&7)*q8 + (p>>3).

// ---------------- fused: CSR histogram (first histBlocks blocks) + embed MFMA ----------------
// Algebraic restructure (round 13): agg = (sum_src h) @ W, so embed no longer
// computes m0 — it only writes x_embed (f32 out + bf16 h0). No LDS needed.
__global__ __launch_bounds__(256) void k_embed_hist(const float* __restrict__ x,
                                                    const unsigned short* __restrict__ W0b,
                                                    unsigned short* __restrict__ hb,
                                                    float* __restrict__ xemb,
                                                    int N,
                                                    const int* __restrict__ dst,
                                                    int* __restrict__ deg,
                                                    unsigned short* __restrict__ rank,
                                                    long long E, int histBlocks, int q8) {
  if ((int)blockIdx.x < histBlocks) {
    long long e = (long long)blockIdx.x * 256 + threadIdx.x;
    if (e < E) {
      int old = atomicAdd(&deg[dst[e]], 1);
      rank[e] = (unsigned short)old;
    }
    return;
  }
  int p = blockIdx.x - histBlocks;
  int T = (p & 7) * q8 + (p >> 3);
  int n0 = T * 64;
  if (n0 >= N) return;
  int t = threadIdx.x;
  int w = t >> 6, l = t & 63;
  int lm = l & 15, lq = l >> 4;
  int j0 = w * 32;
  bf16x8 b0 = *(const bf16x8*)(W0b + (size_t)(j0 + lm) * FDIM + lq * 8);
  bf16x8 b1 = *(const bf16x8*)(W0b + (size_t)(j0 + 16 + lm) * FDIM + lq * 8);
  f32x4 acc0[4], acc1[4];
#pragma unroll
  for (int i = 0; i < 4; ++i) { acc0[i] = (f32x4){0.f,0.f,0.f,0.f}; acc1[i] = (f32x4){0.f,0.f,0.f,0.f}; }
#pragma unroll
  for (int tt = 0; tt < 4; ++tt) {
    int rg = n0 + tt * 16 + lm;
    bf16x8 a = (bf16x8){0,0,0,0,0,0,0,0};
    if (rg < N) {
      const float4* xr = (const float4*)x + (size_t)rg * 8 + lq * 2;
      a = pack_bf16x8(xr[0], xr[1]);
    }
    acc0[tt] = __builtin_amdgcn_mfma_f32_16x16x32_bf16(a, b0, acc0[tt], 0, 0, 0);
    acc1[tt] = __builtin_amdgcn_mfma_f32_16x16x32_bf16(a, b1, acc1[tt], 0, 0, 0);
  }
#pragma unroll
  for (int g = 0; g < 2; ++g) {
    int j = j0 + g * 16 + lm;
#pragma unroll
    for (int tt = 0; tt < 4; ++tt)
#pragma unroll
      for (int r = 0; r < 4; ++r) {
        int node = n0 + tt * 16 + lq * 4 + r;
        if (node < N) {
          float v = g ? acc1[tt][r] : acc0[tt][r];
          float e = fsig(v);
          size_t off = (size_t)node * HDIM + j;
          xemb[off] = e;
          ((__hip_bfloat16*)hb)[off] = __float2bfloat16(e);
        }
      }
  }
}

// ---------------- weight prep: fp32 -> bf16 (W0, GRU mats, conv transpose) ----------------
__global__ __launch_bounds__(256) void k_prep_w(const float* __restrict__ w_ih,
                                                const float* __restrict__ w_hh,
                                                const float* __restrict__ conv_w,
                                                const float* __restrict__ W0,
                                                unsigned short* __restrict__ wIb,
                                                unsigned short* __restrict__ wHb,
                                                unsigned short* __restrict__ convTb,
                                                unsigned short* __restrict__ W0b,
                                                int L) {
  int i = blockIdx.x * 256 + threadIdx.x;
  if (i < HDIM * FDIM) ((__hip_bfloat16*)W0b)[i] = __float2bfloat16(W0[i]);
  if (i < 384 * HDIM) {
    ((__hip_bfloat16*)wIb)[i] = __float2bfloat16(w_ih[i]);
    ((__hip_bfloat16*)wHb)[i] = __float2bfloat16(w_hh[i]);
  }
  int total = L * HDIM * HDIM;
  if (i < total) {
    int l = i >> 14, rem = i & 16383, j = rem >> 7, k = rem & 127;
    ((__hip_bfloat16*)convTb)[i] = __float2bfloat16(conv_w[(l << 14) + (k << 7) + j]);
  }
}

__global__ __launch_bounds__(256) void k_block_sum(const int* __restrict__ deg,
                                                   int* __restrict__ bsum, int N) {
  int base = blockIdx.x * SCAN_CHUNK + threadIdx.x * 8;
  int s = 0;
#pragma unroll
  for (int u = 0; u < 8; ++u) { int i = base + u; if (i < N) s += deg[i]; }
#pragma unroll
  for (int o = 32; o; o >>= 1) s += __shfl_down(s, o, 64);
  __shared__ int wsum[4];
  if ((threadIdx.x & 63) == 0) wsum[threadIdx.x >> 6] = s;
  __syncthreads();
  if (threadIdx.x == 0) bsum[blockIdx.x] = wsum[0] + wsum[1] + wsum[2] + wsum[3];
}

__global__ void k_scan_bsums(int* __restrict__ bsum, int nb) {
  if (blockIdx.x == 0 && threadIdx.x == 0) {
    int run = 0;
    for (int i = 0; i < nb; ++i) { int v = bsum[i]; bsum[i] = run; run += v; }
  }
}

__global__ __launch_bounds__(256) void k_scan_chunks(const int* __restrict__ deg,
                                                     const int* __restrict__ bsum,
                                                     int* __restrict__ rowstart,
                                                     int N, int Etot) {
  __shared__ int ts[256];
  int base = blockIdx.x * SCAN_CHUNK + threadIdx.x * 8;
  int loc[8]; int s = 0;
#pragma unroll
  for (int u = 0; u < 8; ++u) {
    int i = base + u; loc[u] = s;
    s += (i < N) ? deg[i] : 0;
  }
  ts[threadIdx.x] = s;
  __syncthreads();
  for (int o = 1; o < 256; o <<= 1) {
    int v = (threadIdx.x >= o) ? ts[threadIdx.x - o] : 0;
    __syncthreads();
    ts[threadIdx.x] += v;
    __syncthreads();
  }
  int texcl = (threadIdx.x ? ts[threadIdx.x - 1] : 0) + bsum[blockIdx.x];
#pragma unroll
  for (int u = 0; u < 8; ++u) {
    int i = base + u;
    if (i < N) rowstart[i] = texcl + loc[u];
  }
  if (blockIdx.x == 0 && threadIdx.x == 0) rowstart[N] = Etot;
}

// Windowed, atomic-free CSR fill.
__global__ __launch_bounds__(256) void k_csr_fill_win(const int* __restrict__ src,
                                                      const int* __restrict__ dst,
                                                      const unsigned short* __restrict__ rank,
                                                      const int* __restrict__ rowstart,
                                                      int* __restrict__ csr,
                                                      long long E, int N) {
  __shared__ int sd[FILL_CHUNK];
  __shared__ int ss[FILL_CHUNK];
  __shared__ unsigned short sr[FILL_CHUNK];
  long long base = (long long)blockIdx.x * FILL_CHUNK;
  int cnt = (int)((E - base < FILL_CHUNK) ? (E - base) : FILL_CHUNK);
  for (int i = threadIdx.x; i < cnt; i += 256) {
    sd[i] = dst[base + i];
    ss[i] = src[base + i];
    sr[i] = rank[base + i];
  }
  __syncthreads();
  int nw = (N + FILL_WIN - 1) / FILL_WIN;
#pragma unroll 1
  for (int w = 0; w < FILL_WIN; ++w) {
    int lo = w * nw, hi = lo + nw;
    for (int i = threadIdx.x; i < cnt; i += 256) {
      int d = sd[i];
      if (d >= lo && d < hi)
        csr[rowstart[d] + sr[i]] = ss[i];
    }
    __syncthreads();
  }
}

// ---------------- hsum[n] = sum_{row n} h[src]; wave/node, 8 edges x 2KB in flight ----------------
__global__ __launch_bounds__(256) void k_gather(const int* __restrict__ csr,
                                                const int* __restrict__ rowstart,
                                                const unsigned short* __restrict__ m,
                                                unsigned short* __restrict__ agg, int N, int q8) {
  int p = blockIdx.x;
  int G = (p & 7) * q8 * 16 + (p >> 3);
  int wv = threadIdx.x >> 6, l = threadIdx.x & 63;
  int n = G * 4 + wv;
  if (n >= N) return;
  int eq = l >> 3;      // edge slot 0..7
  int jb = l & 7;       // channel group (16 chans, 32B)
  int beg = rowstart[n], end = rowstart[n + 1];
  float acc[16];
#pragma unroll
  for (int i = 0; i < 16; ++i) acc[i] = 0.f;
  for (int e0 = beg; e0 < end; e0 += 8) {
    int e = e0 + eq;
    uint4 v0 = make_uint4(0u, 0u, 0u, 0u);
    uint4 v1 = make_uint4(0u, 0u, 0u, 0u);
    if (e < end) {
      int s = csr[e];
      const uint4* row = (const uint4*)(m + (size_t)s * HDIM + jb * 16);
      v0 = row[0];
      v1 = row[1];
    }
    acc[0]  += __uint_as_float(v0.x << 16);
    acc[1]  += __uint_as_float(v0.x & 0xffff0000u);
    acc[2]  += __uint_as_float(v0.y << 16);
    acc[3]  += __uint_as_float(v0.y & 0xffff0000u);
    acc[4]  += __uint_as_float(v0.z << 16);
    acc[5]  += __uint_as_float(v0.z & 0xffff0000u);
    acc[6]  += __uint_as_float(v0.w << 16);
    acc[7]  += __uint_as_float(v0.w & 0xffff0000u);
    acc[8]  += __uint_as_float(v1.x << 16);
    acc[9]  += __uint_as_float(v1.x & 0xffff0000u);
    acc[10] += __uint_as_float(v1.y << 16);
    acc[11] += __uint_as_float(v1.y & 0xffff0000u);
    acc[12] += __uint_as_float(v1.z << 16);
    acc[13] += __uint_as_float(v1.z & 0xffff0000u);
    acc[14] += __uint_as_float(v1.w << 16);
    acc[15] += __uint_as_float(v1.w & 0xffff0000u);
  }
#pragma unroll
  for (int i = 0; i < 16; ++i) {
    acc[i] += __shfl_xor(acc[i], 8, 64);
    acc[i] += __shfl_xor(acc[i], 16, 64);
    acc[i] += __shfl_xor(acc[i], 32, 64);
  }
  if (eq == 0) {
    union { uint4 v[2]; __hip_bfloat162 h[8]; } o;
#pragma unroll
    for (int i = 0; i < 8; ++i)
      o.h[i] = __float22bfloat162_rn(make_float2(acc[2 * i], acc[2 * i + 1]));
    uint4* dstp = (uint4*)(agg + (size_t)n * HDIM + jb * 16);
    dstp[0] = o.v[0];
    dstp[1] = o.v[1];
  }
}

// ---------------- fused GRU (layers 0..L-2): transform prologue + round-9 core ----------------
// Prologue applies agg = hsum @ conv_w[l] via MFMA (matmul distributes over the
// scatter-sum), replacing the old per-layer m tensor. Core + clustered scalar
// epilogue are the proven round-9 schedule; no m_out write (25.6 MB/layer saved).
__global__ __launch_bounds__(512, 4) void k_gru_mfma(const unsigned short* __restrict__ hsum,
                                                  const unsigned short* __restrict__ hb,
                                                  const unsigned short* __restrict__ wT,
                                                  const unsigned short* __restrict__ wI,
                                                  const unsigned short* __restrict__ wH,
                                                  const float* __restrict__ b_ih,
                                                  const float* __restrict__ b_hh,
                                                  unsigned short* __restrict__ hnewb,
                                                  int N, int q8) {
  __shared__ short sAg[16 * 64 * 8];
  __shared__ short sH[16 * 64 * 8];
  int p = blockIdx.x;
  int T = (p & 7) * q8 + (p >> 3);
  int n0 = T * 64;
  if (n0 >= N) return;
  int t = threadIdx.x;
  stage64(hsum, sAg, n0, N, t);
  stage64(hb, sH, n0, N, t);
  int w = t >> 6, l = t & 63;
  int j0 = w * 16;
  int lm = l & 15, lq = l >> 4;
  int j = j0 + lm;
  float bir = b_ih[j], biz = b_ih[j + 128], bin = b_ih[j + 256];
  float bhr = b_hh[j], bhz = b_hh[j + 128], bhn = b_hh[j + 256];
  __syncthreads();
  // ---- transform prologue: agg = hsum @ conv_w[l] ----
  {
    f32x4 macc[4];
#pragma unroll
    for (int i = 0; i < 4; ++i) macc[i] = (f32x4){0.f,0.f,0.f,0.f};
#pragma unroll
    for (int ks = 0; ks < 4; ++ks) {
      bf16x8 b = *(const bf16x8*)(wT + (size_t)(j0 + lm) * HDIM + ks * 32 + lq * 8);
      int kb = ks * 4 + lq;
#pragma unroll
      for (int tt = 0; tt < 4; ++tt) {
        bf16x8 a = *(const bf16x8*)(sAg + ablk(kb, tt * 16 + lm) * 8);
        macc[tt] = __builtin_amdgcn_mfma_f32_16x16x32_bf16(a, b, macc[tt], 0, 0, 0);
      }
    }
    __syncthreads();   // all hsum reads done; reuse sAg for the agg tile
#pragma unroll
    for (int tt = 0; tt < 4; ++tt)
#pragma unroll
      for (int r = 0; r < 4; ++r) {
        int m = tt * 16 + lq * 4 + r;
        ((__hip_bfloat16*)sAg)[ablk(j >> 3, m) * 8 + (j & 7)] = __float2bfloat16(macc[tt][r]);
      }
  }
  __syncthreads();   // agg tile ready
  f32x4 aR[4], aZ[4], aNi[4], aNh[4];
#pragma unroll
  for (int i = 0; i < 4; ++i) {
    aR[i] = (f32x4){0.f,0.f,0.f,0.f}; aZ[i] = (f32x4){0.f,0.f,0.f,0.f};
    aNi[i] = (f32x4){0.f,0.f,0.f,0.f}; aNh[i] = (f32x4){0.f,0.f,0.f,0.f};
  }
#pragma unroll
  for (int ks = 0; ks < 4; ++ks) {
    size_t rI = (size_t)(j0 + lm) * HDIM + ks * 32 + lq * 8;
    bf16x8 bIr = *(const bf16x8*)(wI + rI);
    bf16x8 bIz = *(const bf16x8*)(wI + rI + 128 * HDIM);
    bf16x8 bIn = *(const bf16x8*)(wI + rI + 256 * HDIM);
    bf16x8 bHr = *(const bf16x8*)(wH + rI);
    bf16x8 bHz = *(const bf16x8*)(wH + rI + 128 * HDIM);
    bf16x8 bHn = *(const bf16x8*)(wH + rI + 256 * HDIM);
    int kb = ks * 4 + lq;
#pragma unroll
    for (int tt = 0; tt < 4; ++tt) {
      bf16x8 a = *(const bf16x8*)(sAg + ablk(kb, tt * 16 + lm) * 8);
      bf16x8 h = *(const bf16x8*)(sH + ablk(kb, tt * 16 + lm) * 8);
      aR[tt] = __builtin_amdgcn_mfma_f32_16x16x32_bf16(a, bIr, aR[tt], 0, 0, 0);
      aR[tt] = __builtin_amdgcn_mfma_f32_16x16x32_bf16(h, bHr, aR[tt], 0, 0, 0);
      aZ[tt] = __builtin_amdgcn_mfma_f32_16x16x32_bf16(a, bIz, aZ[tt], 0, 0, 0);
      aZ[tt] = __builtin_amdgcn_mfma_f32_16x16x32_bf16(h, bHz, aZ[tt], 0, 0, 0);
      aNi[tt] = __builtin_amdgcn_mfma_f32_16x16x32_bf16(a, bIn, aNi[tt], 0, 0, 0);
      aNh[tt] = __builtin_amdgcn_mfma_f32_16x16x32_bf16(h, bHn, aNh[tt], 0, 0, 0);
    }
  }
  // epilogue reads only sH (untouched) + registers; writes global (clustered)
#pragma unroll
  for (int tt = 0; tt < 4; ++tt)
#pragma unroll
    for (int r = 0; r < 4; ++r) {
      int m = tt * 16 + lq * 4 + r;
      int node = n0 + m;
      float hp = __bfloat162float(((const __hip_bfloat16*)sH)[ablk(j >> 3, m) * 8 + (j & 7)]);
      float rg = fsig(aR[tt][r] + bir + bhr);
      float zg = fsig(aZ[tt][r] + biz + bhz);
      float nv = aNi[tt][r] + bin + rg * (aNh[tt][r] + bhn);
      float th = ftanh(nv);
      float hn = (1.f - zg) * th + zg * hp;
      if (node < N)
        ((__hip_bfloat16*)hnewb)[(size_t)node * HDIM + j] = __float2bfloat16(hn);
    }
}

// ---------------- final-layer GRU: transform prologue + core + fused readout ----------------
__global__ __launch_bounds__(512, 4) void k_gru_last(const unsigned short* __restrict__ hsum,
                                                  const unsigned short* __restrict__ hb,
                                                  const unsigned short* __restrict__ wT,
                                                  const unsigned short* __restrict__ wI,
                                                  const unsigned short* __restrict__ wH,
                                                  const float* __restrict__ b_ih,
                                                  const float* __restrict__ b_hh,
                                                  const float* __restrict__ w1,
                                                  const float* __restrict__ b1,
                                                  float* __restrict__ out_raw,
                                                  float* __restrict__ out_unc,
                                                  int N, int q8) {
  __shared__ short sAg[16 * 64 * 8];
  __shared__ short sH[16 * 64 * 8];
  __shared__ float sOut[64];
  int p = blockIdx.x;
  int T = (p & 7) * q8 + (p >> 3);
  int n0 = T * 64;
  if (n0 >= N) return;
  int t = threadIdx.x;
  stage64(hsum, sAg, n0, N, t);
  stage64(hb, sH, n0, N, t);
  if (t < 64) sOut[t] = 0.f;
  int w = t >> 6, l = t & 63;
  int j0 = w * 16;
  int lm = l & 15, lq = l >> 4;
  int j = j0 + lm;
  float bir = b_ih[j], biz = b_ih[j + 128], bin = b_ih[j + 256];
  float bhr = b_hh[j], bhz = b_hh[j + 128], bhn = b_hh[j + 256];
  float w1j = w1[j];
  __syncthreads();
  // ---- transform prologue: agg = hsum @ conv_w[L-1] ----
  {
    f32x4 macc[4];
#pragma unroll
    for (int i = 0; i < 4; ++i) macc[i] = (f32x4){0.f,0.f,0.f,0.f};
#pragma unroll
    for (int ks = 0; ks < 4; ++ks) {
      bf16x8 b = *(const bf16x8*)(wT + (size_t)(j0 + lm) * HDIM + ks * 32 + lq * 8);
      int kb = ks * 4 + lq;
#pragma unroll
      for (int tt = 0; tt < 4; ++tt) {
        bf16x8 a = *(const bf16x8*)(sAg + ablk(kb, tt * 16 + lm) * 8);
        macc[tt] = __builtin_amdgcn_mfma_f32_16x16x32_bf16(a, b, macc[tt], 0, 0, 0);
      }
    }
    __syncthreads();
#pragma unroll
    for (int tt = 0; tt < 4; ++tt)
#pragma unroll
      for (int r = 0; r < 4; ++r) {
        int m = tt * 16 + lq * 4 + r;
        ((__hip_bfloat16*)sAg)[ablk(j >> 3, m) * 8 + (j & 7)] = __float2bfloat16(macc[tt][r]);
      }
  }
  __syncthreads();
  f32x4 aR[4], aZ[4], aNi[4], aNh[4];
#pragma unroll
  for (int i = 0; i < 4; ++i) {
    aR[i] = (f32x4){0.f,0.f,0.f,0.f}; aZ[i] = (f32x4){0.f,0.f,0.f,0.f};
    aNi[i] = (f32x4){0.f,0.f,0.f,0.f}; aNh[i] = (f32x4){0.f,0.f,0.f,0.f};
  }
#pragma unroll
  for (int ks = 0; ks < 4; ++ks) {
    size_t rI = (size_t)(j0 + lm) * HDIM + ks * 32 + lq * 8;
    bf16x8 bIr = *(const bf16x8*)(wI + rI);
    bf16x8 bIz = *(const bf16x8*)(wI + rI + 128 * HDIM);
    bf16x8 bIn = *(const bf16x8*)(wI + rI + 256 * HDIM);
    bf16x8 bHr = *(const bf16x8*)(wH + rI);
    bf16x8 bHz = *(const bf16x8*)(wH + rI + 128 * HDIM);
    bf16x8 bHn = *(const bf16x8*)(wH + rI + 256 * HDIM);
    int kb = ks * 4 + lq;
#pragma unroll
    for (int tt = 0; tt < 4; ++tt) {
      bf16x8 a = *(const bf16x8*)(sAg + ablk(kb, tt * 16 + lm) * 8);
      bf16x8 h = *(const bf16x8*)(sH + ablk(kb, tt * 16 + lm) * 8);
      aR[tt] = __builtin_amdgcn_mfma_f32_16x16x32_bf16(a, bIr, aR[tt], 0, 0, 0);
      aR[tt] = __builtin_amdgcn_mfma_f32_16x16x32_bf16(h, bHr, aR[tt], 0, 0, 0);
      aZ[tt] = __builtin_amdgcn_mfma_f32_16x16x32_bf16(a, bIz, aZ[tt], 0, 0, 0);
      aZ[tt] = __builtin_amdgcn_mfma_f32_16x16x32_bf16(h, bHz, aZ[tt], 0, 0, 0);
      aNi[tt] = __builtin_amdgcn_mfma_f32_16x16x32_bf16(a, bIn, aNi[tt], 0, 0, 0);
      aNh[tt] = __builtin_amdgcn_mfma_f32_16x16x32_bf16(h, bHn, aNh[tt], 0, 0, 0);
    }
  }
  __syncthreads();
#pragma unroll
  for (int tt = 0; tt < 4; ++tt)
#pragma unroll
    for (int r = 0; r < 4; ++r) {
      int m = tt * 16 + lq * 4 + r;
      int node = n0 + m;
      float hp = __bfloat162float(((const __hip_bfloat16*)sH)[ablk(j >> 3, m) * 8 + (j & 7)]);
      float rg = fsig(aR[tt][r] + bir + bhr);
      float zg = fsig(aZ[tt][r] + biz + bhz);
      float nv = aNi[tt][r] + bin + rg * (aNh[tt][r] + bhn);
      float th = ftanh(nv);
      float hn = (1.f - zg) * th + zg * hp;
      float prt = (node < N) ? fmaxf(hn, 0.f) * w1j : 0.f;
      prt += __shfl_xor(prt, 1, 64);
      prt += __shfl_xor(prt, 2, 64);
      prt += __shfl_xor(prt, 4, 64);
      prt += __shfl_xor(prt, 8, 64);
      if (lm == 0) atomicAdd(&sOut[m], prt);
    }
  __syncthreads();
  if (t < 64) {
    int node = n0 + t;
    if (node < N) {
      float o = sOut[t] + b1[0];
      out_raw[node] = o;
      out_unc[node] = o;
    }
  }
}

__global__ __launch_bounds__(256) void k_graph_reduce(const float* __restrict__ out_raw,
                                                      const int* __restrict__ batch,
                                                      float* __restrict__ gsum,
                                                      float* __restrict__ gcnt,
                                                      int N) {
  __shared__ float ls[GGR], lc[GGR];
  int t = threadIdx.x;
  if (t < GGR) { ls[t] = 0.f; lc[t] = 0.f; }
  __syncthreads();
  for (int n = blockIdx.x * 256 + t; n < N; n += gridDim.x * 256) {
    int g = batch[n];
    atomicAdd(&ls[g], out_raw[n]);
    atomicAdd(&lc[g], 1.f);
  }
  __syncthreads();
  if (t < GGR) {
    unsafeAtomicAdd(&gsum[t], ls[t]);
    unsafeAtomicAdd(&gcnt[t], lc[t]);
  }
}

__global__ __launch_bounds__(256) void k_correct(const float* __restrict__ out_raw,
                                                 const int* __restrict__ batch,
                                                 const float* __restrict__ gsum,
                                                 const float* __restrict__ gcnt,
                                                 float* __restrict__ corrected, int N) {
  int n = blockIdx.x * 256 + threadIdx.x;
  if (n < N) {
    int g = batch[n];
    corrected[n] = out_raw[n] - gsum[g] / fmaxf(gcnt[g], 1.f);
  }
}

extern "C" void kernel_launch(void* const* d_in, const int* in_sizes, int n_in,
                              void* d_out, int out_size, void* d_ws, size_t ws_size,
                              hipStream_t stream) {
  const float* x      = (const float*)d_in[0];
  const int*   ei     = (const int*)d_in[1];
  const int*   batch  = (const int*)d_in[2];
  const float* W0     = (const float*)d_in[4];
  const float* conv_w = (const float*)d_in[5];
  const float* w_ih   = (const float*)d_in[6];
  const float* b_ih   = (const float*)d_in[7];
  const float* w_hh   = (const float*)d_in[8];
  const float* b_hh   = (const float*)d_in[9];
  const float* lin1_w = (const float*)d_in[10];
  const float* lin1_b = (const float*)d_in[11];

  int N = in_sizes[0] / FDIM;
  long long E = in_sizes[1] / 2;
  int L = in_sizes[5] / (HDIM * HDIM);

  const int* src = ei;
  const int* dstv = ei + E;

  float* out_corrected = (float*)d_out;
  float* out_xemb = out_corrected + N;
  float* out_unc  = out_xemb + (size_t)N * HDIM;

  char* p = (char*)d_ws;
  unsigned short* x0 = (unsigned short*)p; p += (size_t)N * HDIM * 2;
  unsigned short* x1 = (unsigned short*)p; p += (size_t)N * HDIM * 2;
  unsigned short* x2 = (unsigned short*)p; p += (size_t)N * HDIM * 2;
  float* out_raw = (float*)p;        p += (size_t)((N + 3) & ~3) * 4;
  float* gsum = (float*)p;           p += GGR * 4;
  float* gcnt = (float*)p;           p += GGR * 4;
  int* deg = (int*)p;                p += (size_t)((N + 3) & ~3) * 4;
  int* rowstart = (int*)p;           p += (size_t)(N + 4) * 4;
  int nb = (N + SCAN_CHUNK - 1) / SCAN_CHUNK;
  int* bsum = (int*)p;               p += (size_t)((nb + 63) & ~63) * 4;
  int* csr = (int*)p;                p += (size_t)E * 4;
  unsigned short* rankb = (unsigned short*)p;  p += (size_t)((E + 3) & ~3) * 2;
  unsigned short* wIb = (unsigned short*)p;    p += 384 * HDIM * 2;
  unsigned short* wHb = (unsigned short*)p;    p += 384 * HDIM * 2;
  unsigned short* convTb = (unsigned short*)p; p += (size_t)L * HDIM * HDIM * 2;
  unsigned short* W0b = (unsigned short*)p;

  int prep_total = (384 * HDIM > L * HDIM * HDIM) ? 384 * HDIM : L * HDIM * HDIM;
  k_prep_w<<<(prep_total + 255) / 256, 256, 0, stream>>>(w_ih, w_hh, conv_w, W0, wIb, wHb, convTb, W0b, L);

  hipMemsetAsync(deg, 0, (size_t)N * sizeof(int), stream);
  hipMemsetAsync(gsum, 0, 2 * GGR * sizeof(float), stream);

  int nblk = (N + 63) / 64;
  int TP = (nblk + 7) & ~7;   // tile count padded to multiple of 8 XCDs
  int q8 = TP / 8;
  int histBlocks = (int)((E + 255) / 256);
  // fused: hist (scatter atomics) overlapped with embed (MFMA) in one launch
  k_embed_hist<<<histBlocks + TP, 256, 0, stream>>>(x, W0b, x0, out_xemb, N,
                                                    dstv, deg, rankb, E, histBlocks, q8);

  k_block_sum<<<nb, 256, 0, stream>>>(deg, bsum, N);
  k_scan_bsums<<<1, 64, 0, stream>>>(bsum, nb);
  k_scan_chunks<<<nb, 256, 0, stream>>>(deg, bsum, rowstart, N, (int)E);
  k_csr_fill_win<<<(int)((E + FILL_CHUNK - 1) / FILL_CHUNK), 256, 0, stream>>>(
      src, dstv, rankb, rowstart, csr, E, N);

  unsigned short* Hb = x0;  // current h (bf16)
  unsigned short* Fb = x1;  // next h
  for (int l = 0; l < L; ++l) {
    // hsum_l = scatter-sum of h_l rows (transform deferred into the GRU)
    k_gather<<<TP * 16, 256, 0, stream>>>(csr, rowstart, Hb, x2, N, q8);
    const unsigned short* wTl = convTb + (size_t)l * HDIM * HDIM;
    if (l + 1 < L) {
      k_gru_mfma<<<TP, 512, 0, stream>>>(x2, Hb, wTl, wIb, wHb, b_ih, b_hh, Fb, N, q8);
      unsigned short* tmp = Hb; Hb = Fb; Fb = tmp;
    } else {
      k_gru_last<<<TP, 512, 0, stream>>>(x2, Hb, wTl, wIb, wHb, b_ih, b_hh,
                                         lin1_w, lin1_b, out_raw, out_unc, N, q8);
    }
  }

  k_graph_reduce<<<256, 256, 0, stream>>>(out_raw, batch, gsum, gcnt, N);
  k_correct<<<(N + 255) / 256, 256, 0, stream>>>(out_raw, batch, gsum, gcnt, out_corrected, N);
}